// Round 7
// baseline (568.762 us; speedup 1.0000x reference)
//
#include <hip/hip_runtime.h>

// GraphSAGE (pool aggregator, 2 layers) on MI355X.
// Round 7: fuse gather_max into the self+neigh MFMA GEMM.
//   Evidence (r6): gather is fabric-service-bound (~3.5 TB/s random 64B
//   lines; 4x ILP gained only 3%). So: stop paying gather and GEMM in
//   sequence, and stop round-tripping agg (25 MB write + 25.6 MB read).
//   gemm_gather_kernel: per 128-row block, each wave gathers its 32 agg rows
//   into LDS (132-short stride: A-frag ds_read_b128 lands 2 lanes/bank =
//   free), then pair-0 MFMA (self, A from global) + pair-1 MFMA (neigh, A
//   from gathered LDS). 2 blocks/CU -> one block's MFMA overlaps the other's
//   gather. Deletes standalone gather kernels + agg buffer.
// CSR build (XCD-local two-level binning) and pool GEMMs unchanged.

#define N_FEAT 128
#define NWG_A 256
#define BSHIFT 10            // 1024 nodes per bucket
#define NBMAX 128

typedef __attribute__((ext_vector_type(8))) short bf16x8;            // 8 bf16 = 4 VGPRs
typedef __attribute__((ext_vector_type(8))) unsigned short u16x8;    // 16 B
typedef __attribute__((ext_vector_type(4))) float f32x4;

static __device__ __forceinline__ unsigned short f2bf(float f) {
    unsigned u = __float_as_uint(f);
    unsigned r = (u + 0x7fffu + ((u >> 16) & 1u)) >> 16;   // RNE
    return (unsigned short)r;
}

// ---------------- prep: weights -> bf16 (no transpose), fused biases ----------------
__global__ void prep_kernel(const float* __restrict__ pw1, const float* __restrict__ sw1,
                            const float* __restrict__ nw1, const float* __restrict__ pw2,
                            const float* __restrict__ sw2, const float* __restrict__ nw2,
                            const float* __restrict__ sb1, const float* __restrict__ nb1,
                            const float* __restrict__ sb2, const float* __restrict__ nb2,
                            unsigned short* __restrict__ wb_p1, unsigned short* __restrict__ wb_s1,
                            unsigned short* __restrict__ wb_n1, unsigned short* __restrict__ wb_p2,
                            unsigned short* __restrict__ wb_s2, unsigned short* __restrict__ wb_n2,
                            float* __restrict__ b_sn1, float* __restrict__ b_sn2)
{
    int t = blockIdx.x * 256 + threadIdx.x;
    if (t < 16384) {
        wb_p1[t] = f2bf(pw1[t]);
        wb_s1[t] = f2bf(sw1[t]);
        wb_n1[t] = f2bf(nw1[t]);
        wb_p2[t] = f2bf(pw2[t]);
    }
    if (t < 6144) {                       // 48x128, rows 40..47 zero-padded
        int row = t >> 7;
        wb_s2[t] = (row < 40) ? f2bf(sw2[t]) : 0;
        wb_n2[t] = (row < 40) ? f2bf(nw2[t]) : 0;
    }
    if (t < 128) b_sn1[t] = sb1[t] + nb1[t];
    if (t < 64)  b_sn2[t] = (t < 40) ? (sb2[t] + nb2[t]) : 0.f;
}

__global__ void f2b_kernel(const float4* __restrict__ in, ushort4* __restrict__ out, int n)
{
    int i = blockIdx.x * 256 + threadIdx.x;
    if (i < n) {
        float4 v = in[i];
        ushort4 o;
        o.x = f2bf(v.x); o.y = f2bf(v.y); o.z = f2bf(v.z); o.w = f2bf(v.w);
        out[i] = o;
    }
}

// ---------------- CSR build: two-level XCD-local binning (unchanged) ----------------
__global__ __launch_bounds__(256) void bin_count_kernel(const int* __restrict__ dst,
                                                        int* __restrict__ wgcnt,
                                                        int E, int NB)
{
    __shared__ int cnt[NBMAX];
    const int wg = blockIdx.x, tid = threadIdx.x;
    if (tid < NB) cnt[tid] = 0;
    __syncthreads();
    const int slab = (E + NWG_A - 1) / NWG_A;
    const int e0 = wg * slab;
    const int e1 = min(e0 + slab, E);
    for (int e = e0 + tid; e < e1; e += 256)
        atomicAdd(&cnt[dst[e] >> BSHIFT], 1);
    __syncthreads();
    if (tid < NB) wgcnt[tid * NWG_A + wg] = cnt[tid];
}

__global__ __launch_bounds__(256) void bin_scan_kernel(const int* __restrict__ wgcnt,
                                                       int* __restrict__ binoff, int NB)
{
    __shared__ int sh[256];
    const int t = threadIdx.x;
    const int base = t * NB;
    int s = 0;
    for (int k = 0; k < NB; k++) s += wgcnt[base + k];
    sh[t] = s;
    __syncthreads();
    for (int off = 1; off < 256; off <<= 1) {
        int x = (t >= off) ? sh[t - off] : 0;
        __syncthreads();
        sh[t] += x;
        __syncthreads();
    }
    int run = sh[t] - s;
    for (int k = 0; k < NB; k++) {
        int v = wgcnt[base + k];
        binoff[base + k] = run;
        run += v;
    }
    if (t == 255) binoff[NB * NWG_A] = run;  // == E
}

__global__ __launch_bounds__(256) void bin_scatter_kernel(const int* __restrict__ src,
                                                          const int* __restrict__ dst,
                                                          const int* __restrict__ binoff,
                                                          unsigned* __restrict__ binned,
                                                          int E, int NB)
{
    __shared__ int cur[NBMAX];
    const int wg = blockIdx.x, tid = threadIdx.x;
    if (tid < NB) cur[tid] = binoff[tid * NWG_A + wg];
    __syncthreads();
    const int slab = (E + NWG_A - 1) / NWG_A;
    const int e0 = wg * slab;
    const int e1 = min(e0 + slab, E);
    for (int e = e0 + tid; e < e1; e += 256) {
        int d = dst[e];
        int b = d >> BSHIFT;
        unsigned rec = ((unsigned)(d & ((1 << BSHIFT) - 1)) << 17) | (unsigned)src[e];
        int p = atomicAdd(&cur[b], 1);
        binned[p] = rec;
    }
}

__global__ __launch_bounds__(256) void csr_build_kernel(const unsigned* __restrict__ binned,
                                                        const int* __restrict__ binoff,
                                                        int* __restrict__ csr,
                                                        int* __restrict__ offsets,
                                                        int* __restrict__ counts, int M)
{
    __shared__ int cnt[1 << BSHIFT];
    __shared__ int scn[1 << BSHIFT];
    __shared__ int sh[256];
    const int b = blockIdx.x, t = threadIdx.x;
    const int rs = binoff[b * NWG_A];
    const int re = binoff[(b + 1) * NWG_A];

    for (int j = t; j < (1 << BSHIFT); j += 256) cnt[j] = 0;
    __syncthreads();
    for (int i = rs + t; i < re; i += 256)
        atomicAdd(&cnt[binned[i] >> 17], 1);
    __syncthreads();

    const int base4 = t * 4;
    int v[4];
#pragma unroll
    for (int k = 0; k < 4; k++) v[k] = cnt[base4 + k];
    int s = v[0] + v[1] + v[2] + v[3];
    sh[t] = s;
    __syncthreads();
    for (int off = 1; off < 256; off <<= 1) {
        int x = (t >= off) ? sh[t - off] : 0;
        __syncthreads();
        sh[t] += x;
        __syncthreads();
    }
    int run = sh[t] - s;
#pragma unroll
    for (int k = 0; k < 4; k++) {
        scn[base4 + k] = run;
        run += v[k];
    }

    const int node0 = b << BSHIFT;
#pragma unroll
    for (int k = 0; k < 4; k++) {
        int j = base4 + k;
        int node = node0 + j;
        if (node < M) {
            counts[node] = v[k];
            offsets[node] = rs + scn[j];
        }
    }
    __syncthreads();

    for (int i = rs + t; i < re; i += 256) {
        unsigned r = binned[i];
        int p = atomicAdd(&scn[r >> 17], 1);
        csr[rs + p] = (int)(r & 0x1FFFFu);
    }
}

// ---------------- pool GEMM: bf16 MFMA, A direct from global, B-only LDS ----------------
template<int NT, bool RELU, bool F32OUT>
__global__ __launch_bounds__(256, 4) void mfma_gemm_kernel(
    const unsigned short* __restrict__ A0, const unsigned short* __restrict__ B0,
    const float* __restrict__ bias, void* __restrict__ Cout, int M, int Nout)
{
    constexpr int NR = NT * 16;
    __shared__ unsigned short Bs[NR * 136];
    __shared__ float BsF[NR];

    const int tid = threadIdx.x;
    const int w = tid >> 6, lane = tid & 63;
    const int q = lane >> 4, r16 = lane & 15;
    const int m0 = blockIdx.x * 128;

    if (tid < NR) BsF[tid] = (tid < Nout) ? bias[tid] : 0.f;

    int rowA[2];
#pragma unroll
    for (int rt = 0; rt < 2; rt++) {
        int r = m0 + w * 32 + rt * 16 + r16;
        rowA[rt] = r < M ? r : (M - 1);
    }

    f32x4 acc[2][NT];
#pragma unroll
    for (int i = 0; i < 2; i++)
#pragma unroll
        for (int j = 0; j < NT; j++) acc[i][j] = (f32x4){0.f, 0.f, 0.f, 0.f};

    for (int j = tid; j < NR * 16; j += 256) {
        int row = j >> 4, cc = j & 15;
        uint4 v = *(const uint4*)&B0[(size_t)row * 128 + cc * 8];
        *(uint4*)&Bs[row * 136 + cc * 8] = v;
    }
    __syncthreads();

#pragma unroll
    for (int k0 = 0; k0 < 128; k0 += 32) {
        bf16x8 af[2];
#pragma unroll
        for (int rt = 0; rt < 2; rt++)
            af[rt] = *(const bf16x8*)&A0[(size_t)rowA[rt] * 128 + k0 + q * 8];
#pragma unroll
        for (int ct = 0; ct < NT; ct++) {
            bf16x8 bfr = *(const bf16x8*)&Bs[(ct * 16 + r16) * 136 + k0 + q * 8];
#pragma unroll
            for (int rt = 0; rt < 2; rt++)
                acc[rt][ct] = __builtin_amdgcn_mfma_f32_16x16x32_bf16(
                    af[rt], bfr, acc[rt][ct], 0, 0, 0);
        }
    }

#pragma unroll
    for (int rt = 0; rt < 2; rt++) {
#pragma unroll
        for (int ct = 0; ct < NT; ct++) {
            int col = ct * 16 + r16;
#pragma unroll
            for (int r = 0; r < 4; r++) {
                int grow = m0 + w * 32 + rt * 16 + q * 4 + r;
                float v = acc[rt][ct][r] + BsF[col];
                if (RELU) v = fmaxf(v, 0.f);
                if (grow < M && col < Nout) {
                    if (F32OUT)
                        ((float*)Cout)[(size_t)grow * Nout + col] = v;
                    else
                        ((unsigned short*)Cout)[(size_t)grow * Nout + col] = f2bf(v);
                }
            }
        }
    }
}

// ---------------- fused gather-max + self/neigh GEMM ----------------
// C[M,Nout] = act( A0 @ B0^T + gathermax(m)[M] @ B1^T + bias )
// Each wave gathers its 32 dst rows' agg (packed-u16 max over csr neighbors)
// into LDS (132-short stride), then pair-0 MFMA (A0 global) and pair-1 MFMA
// (A from Agg LDS). Bs restaged between pairs (B tiny, L2-hot).
template<int NT, bool RELU, bool F32OUT>
__global__ __launch_bounds__(256, 2) void gemm_gather_kernel(
    const unsigned short* __restrict__ A0, const unsigned short* __restrict__ B0,
    const unsigned short* __restrict__ B1, const unsigned short* __restrict__ m,
    const int* __restrict__ csr, const int* __restrict__ offsets,
    const int* __restrict__ counts,
    const float* __restrict__ bias, void* __restrict__ Cout, int M, int Nout)
{
    constexpr int NR = NT * 16;
    __shared__ unsigned short Bs[NR * 136];
    __shared__ unsigned short Agg[128 * 132];   // stride 132 shorts = 66 dwords
    __shared__ float BsF[NR];

    const int tid = threadIdx.x;
    const int w = tid >> 6, lane = tid & 63;
    const int q = lane >> 4, r16 = lane & 15;
    const int m0 = blockIdx.x * 128;

    if (tid < NR) BsF[tid] = (tid < Nout) ? bias[tid] : 0.f;

    // stage Bs = B0 (self weights)
    for (int j = tid; j < NR * 16; j += 256) {
        int row = j >> 4, cc = j & 15;
        uint4 v = *(const uint4*)&B0[(size_t)row * 128 + cc * 8];
        *(uint4*)&Bs[row * 136 + cc * 8] = v;
    }

    // ---- gather this wave's 32 agg rows into Agg LDS ----
    {
        const u16x8* __restrict__ m16 = (const u16x8*)m;
        const int g = q, c = r16;
        // prefetch deg/off for all 32 nodes of this wave
        int nodeL = m0 + w * 32 + (lane & 31);
        int degL = 0, offL = 0;
        if (nodeL < M) { degL = counts[nodeL]; offL = offsets[nodeL]; }
        for (int n = 0; n < 32; n++) {
            int deg = __shfl(degL, n);
            int start = __shfl(offL, n);
            u16x8 acc = (u16x8){0, 0, 0, 0, 0, 0, 0, 0};
            for (int j0 = 0; j0 < deg; j0 += 64) {
                int nb = deg - j0;
                if (nb > 64) nb = 64;
                int sl = csr[start + j0 + (lane < nb ? lane : nb - 1)];
                for (int j = 0; j < nb; j += 4) {
                    int jj = j + g;
                    if (jj >= nb) jj = nb - 1;          // max idempotent
                    int s = __shfl(sl, jj);
                    u16x8 v = m16[(size_t)s * 16 + c];
                    acc = __builtin_elementwise_max(acc, v);
                }
            }
            // merge the 4 lane groups
#pragma unroll
            for (int d = 16; d <= 32; d <<= 1) {
                int4 a = *(int4*)&acc;
                int4 t;
                t.x = __shfl_xor(a.x, d);
                t.y = __shfl_xor(a.y, d);
                t.z = __shfl_xor(a.z, d);
                t.w = __shfl_xor(a.w, d);
                acc = __builtin_elementwise_max(acc, *(u16x8*)&t);
            }
            if (g == 0) *(u16x8*)&Agg[(w * 32 + n) * 132 + c * 8] = acc;
        }
    }
    __syncthreads();

    int rowA[2];
#pragma unroll
    for (int rt = 0; rt < 2; rt++) {
        int r = m0 + w * 32 + rt * 16 + r16;
        rowA[rt] = r < M ? r : (M - 1);
    }

    f32x4 acc[2][NT];
#pragma unroll
    for (int i = 0; i < 2; i++)
#pragma unroll
        for (int j = 0; j < NT; j++) acc[i][j] = (f32x4){0.f, 0.f, 0.f, 0.f};

    // pair 0: self — A0 from global, Bs=B0
#pragma unroll
    for (int k0 = 0; k0 < 128; k0 += 32) {
        bf16x8 af[2];
#pragma unroll
        for (int rt = 0; rt < 2; rt++)
            af[rt] = *(const bf16x8*)&A0[(size_t)rowA[rt] * 128 + k0 + q * 8];
#pragma unroll
        for (int ct = 0; ct < NT; ct++) {
            bf16x8 bfr = *(const bf16x8*)&Bs[(ct * 16 + r16) * 136 + k0 + q * 8];
#pragma unroll
            for (int rt = 0; rt < 2; rt++)
                acc[rt][ct] = __builtin_amdgcn_mfma_f32_16x16x32_bf16(
                    af[rt], bfr, acc[rt][ct], 0, 0, 0);
        }
    }
    __syncthreads();                 // Bs consumed
    // restage Bs = B1 (neigh weights)
    for (int j = tid; j < NR * 16; j += 256) {
        int row = j >> 4, cc = j & 15;
        uint4 v = *(const uint4*)&B1[(size_t)row * 128 + cc * 8];
        *(uint4*)&Bs[row * 136 + cc * 8] = v;
    }
    __syncthreads();

    // pair 1: neigh — A from gathered Agg LDS
#pragma unroll
    for (int k0 = 0; k0 < 128; k0 += 32) {
        bf16x8 af[2];
#pragma unroll
        for (int rt = 0; rt < 2; rt++)
            af[rt] = *(const bf16x8*)&Agg[(w * 32 + rt * 16 + r16) * 132 + k0 + q * 8];
#pragma unroll
        for (int ct = 0; ct < NT; ct++) {
            bf16x8 bfr = *(const bf16x8*)&Bs[(ct * 16 + r16) * 136 + k0 + q * 8];
#pragma unroll
            for (int rt = 0; rt < 2; rt++)
                acc[rt][ct] = __builtin_amdgcn_mfma_f32_16x16x32_bf16(
                    af[rt], bfr, acc[rt][ct], 0, 0, 0);
        }
    }

    // epilogue: C/D layout col=lane&15, row=(lane>>4)*4+reg
#pragma unroll
    for (int rt = 0; rt < 2; rt++) {
#pragma unroll
        for (int ct = 0; ct < NT; ct++) {
            int col = ct * 16 + r16;
#pragma unroll
            for (int r = 0; r < 4; r++) {
                int grow = m0 + w * 32 + rt * 16 + q * 4 + r;
                float v = acc[rt][ct][r] + BsF[col];
                if (RELU) v = fmaxf(v, 0.f);
                if (grow < M && col < Nout) {
                    if (F32OUT)
                        ((float*)Cout)[(size_t)grow * Nout + col] = v;
                    else
                        ((unsigned short*)Cout)[(size_t)grow * Nout + col] = f2bf(v);
                }
            }
        }
    }
}

extern "C" void kernel_launch(void* const* d_in, const int* in_sizes, int n_in,
                              void* d_out, int out_size, void* d_ws, size_t ws_size,
                              hipStream_t stream)
{
    const float* in_feat = (const float*)d_in[0];
    const int*   src     = (const int*)d_in[1];
    const int*   dst     = (const int*)d_in[2];
    const float* pw1 = (const float*)d_in[3];  const float* pb1 = (const float*)d_in[4];
    const float* sw1 = (const float*)d_in[5];  const float* sb1 = (const float*)d_in[6];
    const float* nw1 = (const float*)d_in[7];  const float* nb1 = (const float*)d_in[8];
    const float* pw2 = (const float*)d_in[9];  const float* pb2 = (const float*)d_in[10];
    const float* sw2 = (const float*)d_in[11]; const float* sb2 = (const float*)d_in[12];
    const float* nw2 = (const float*)d_in[13]; const float* nb2 = (const float*)d_in[14];
    float* out = (float*)d_out;

    const int M = in_sizes[0] / N_FEAT;   // 100000 nodes
    const int E = in_sizes[1];            // 1600000 edges
    const int NB = (M + (1 << BSHIFT) - 1) >> BSHIFT;   // 98 buckets

    // ---- workspace layout (256B-aligned regions) ----
    char* base = (char*)d_ws;
    size_t off = 0;
    auto alloc = [&](size_t bytes) { char* p = base + off; off = (off + bytes + 255) & ~(size_t)255; return p; };
    unsigned short* wb_p1 = (unsigned short*)alloc(16384 * 2);
    unsigned short* wb_s1 = (unsigned short*)alloc(16384 * 2);
    unsigned short* wb_n1 = (unsigned short*)alloc(16384 * 2);
    unsigned short* wb_p2 = (unsigned short*)alloc(16384 * 2);
    unsigned short* wb_s2 = (unsigned short*)alloc(6144 * 2);
    unsigned short* wb_n2 = (unsigned short*)alloc(6144 * 2);
    float* b_sn1 = (float*)alloc(128 * 4);
    float* b_sn2 = (float*)alloc(64 * 4);
    unsigned short* in_b = (unsigned short*)alloc((size_t)M * 128 * 2);
    unsigned short* mb   = (unsigned short*)alloc((size_t)M * 128 * 2);
    unsigned short* h1   = (unsigned short*)alloc((size_t)M * 128 * 2);
    int* counts  = (int*)alloc((size_t)M * 4);
    int* offsets = (int*)alloc((size_t)M * 4);
    int* wgcnt   = (int*)alloc((size_t)NB * NWG_A * 4);
    int* binoff  = (int*)alloc(((size_t)NB * NWG_A + 1) * 4);
    unsigned* binned = (unsigned*)alloc((size_t)E * 4);
    int* csr     = (int*)alloc((size_t)E * 4);

    const int gemm_grid = (M + 127) / 128;
    const int nf4 = M * 128 / 4;

    prep_kernel<<<64, 256, 0, stream>>>(pw1, sw1, nw1, pw2, sw2, nw2,
                                        sb1, nb1, sb2, nb2,
                                        wb_p1, wb_s1, wb_n1, wb_p2, wb_s2, wb_n2,
                                        b_sn1, b_sn2);
    f2b_kernel<<<(nf4 + 255) / 256, 256, 0, stream>>>((const float4*)in_feat, (ushort4*)in_b, nf4);

    // ---- CSR build: XCD-local two-level binning ----
    bin_count_kernel<<<NWG_A, 256, 0, stream>>>(dst, wgcnt, E, NB);
    bin_scan_kernel<<<1, 256, 0, stream>>>(wgcnt, binoff, NB);
    bin_scatter_kernel<<<NWG_A, 256, 0, stream>>>(src, dst, binoff, binned, E, NB);
    csr_build_kernel<<<NB, 256, 0, stream>>>(binned, binoff, csr, offsets, counts, M);

    // ---- Layer 1 ----
    mfma_gemm_kernel<8, true, false><<<gemm_grid, 256, 0, stream>>>(
        in_b, wb_p1, pb1, mb, M, 128);
    gemm_gather_kernel<8, true, false><<<gemm_grid, 256, 0, stream>>>(
        in_b, wb_s1, wb_n1, mb, csr, offsets, counts, b_sn1, h1, M, 128);

    // ---- Layer 2 ----
    mfma_gemm_kernel<8, true, false><<<gemm_grid, 256, 0, stream>>>(
        h1, wb_p2, pb2, mb, M, 128);
    gemm_gather_kernel<3, false, true><<<gemm_grid, 256, 0, stream>>>(
        h1, wb_s2, wb_n2, mb, csr, offsets, counts, b_sn2, out, M, 40);
}

// Round 8
// 393.843 us; speedup vs baseline: 1.4441x; 1.4441x over previous
//
#include <hip/hip_runtime.h>

// GraphSAGE (pool aggregator, 2 layers) on MI355X.
// Round 8: revert r7 fusion (gather needs high occupancy: 16.8% occ ->
// 1.34 TB/s vs 70% occ -> 3.5 TB/s). Keep r6 structure; harvest:
//   - delete f2b: GEMMs convert f32 A-fragments on the fly (same RNE)
//   - sn_pool: chain pool2 GEMM after self+neigh GEMM via LDS h1 tile
//     (kills pool2's h1 re-read + a dispatch; MFMA phases tolerate 2 blk/CU)
//   - merge prep + bin_count into one dispatch
// CSR build (XCD-local two-level binning) and gather unchanged from r6.

#define N_FEAT 128
#define NWG_A 256
#define BSHIFT 10            // 1024 nodes per bucket
#define NBMAX 128

typedef __attribute__((ext_vector_type(8))) short bf16x8;            // 8 bf16 = 4 VGPRs
typedef __attribute__((ext_vector_type(8))) unsigned short u16x8;    // 16 B
typedef __attribute__((ext_vector_type(4))) float f32x4;

static __device__ __forceinline__ unsigned short f2bf(float f) {
    unsigned u = __float_as_uint(f);
    unsigned r = (u + 0x7fffu + ((u >> 16) & 1u)) >> 16;   // RNE
    return (unsigned short)r;
}

static __device__ __forceinline__ bf16x8 loadA_f32(const float* __restrict__ A, size_t idx) {
    float4 a = *(const float4*)&A[idx];
    float4 b = *(const float4*)&A[idx + 4];
    bf16x8 r;
    r[0] = (short)f2bf(a.x); r[1] = (short)f2bf(a.y);
    r[2] = (short)f2bf(a.z); r[3] = (short)f2bf(a.w);
    r[4] = (short)f2bf(b.x); r[5] = (short)f2bf(b.y);
    r[6] = (short)f2bf(b.z); r[7] = (short)f2bf(b.w);
    return r;
}

// ---------------- prep (weights->bf16, fused biases) + bin_count merged ----------------
__global__ __launch_bounds__(256) void prep_bin_kernel(
    const float* __restrict__ pw1, const float* __restrict__ sw1,
    const float* __restrict__ nw1, const float* __restrict__ pw2,
    const float* __restrict__ sw2, const float* __restrict__ nw2,
    const float* __restrict__ sb1, const float* __restrict__ nb1,
    const float* __restrict__ sb2, const float* __restrict__ nb2,
    unsigned short* __restrict__ wb_p1, unsigned short* __restrict__ wb_s1,
    unsigned short* __restrict__ wb_n1, unsigned short* __restrict__ wb_p2,
    unsigned short* __restrict__ wb_s2, unsigned short* __restrict__ wb_n2,
    float* __restrict__ b_sn1, float* __restrict__ b_sn2,
    const int* __restrict__ dst, int* __restrict__ wgcnt, int E, int NB)
{
    __shared__ int cnt[NBMAX];
    if (blockIdx.x < NWG_A) {
        // bin_count body
        const int wg = blockIdx.x, tid = threadIdx.x;
        if (tid < NB) cnt[tid] = 0;
        __syncthreads();
        const int slab = (E + NWG_A - 1) / NWG_A;
        const int e0 = wg * slab;
        const int e1 = min(e0 + slab, E);
        for (int e = e0 + tid; e < e1; e += 256)
            atomicAdd(&cnt[dst[e] >> BSHIFT], 1);
        __syncthreads();
        if (tid < NB) wgcnt[tid * NWG_A + wg] = cnt[tid];
    } else {
        // prep body
        int t = (blockIdx.x - NWG_A) * 256 + threadIdx.x;
        if (t < 16384) {
            wb_p1[t] = f2bf(pw1[t]);
            wb_s1[t] = f2bf(sw1[t]);
            wb_n1[t] = f2bf(nw1[t]);
            wb_p2[t] = f2bf(pw2[t]);
        }
        if (t < 6144) {                   // 48x128, rows 40..47 zero-padded
            int row = t >> 7;
            wb_s2[t] = (row < 40) ? f2bf(sw2[t]) : 0;
            wb_n2[t] = (row < 40) ? f2bf(nw2[t]) : 0;
        }
        if (t < 128) b_sn1[t] = sb1[t] + nb1[t];
        if (t < 64)  b_sn2[t] = (t < 40) ? (sb2[t] + nb2[t]) : 0.f;
    }
}

// ---------------- CSR build: two-level XCD-local binning (unchanged) ----------------
__global__ __launch_bounds__(256) void bin_scan_kernel(const int* __restrict__ wgcnt,
                                                       int* __restrict__ binoff, int NB)
{
    __shared__ int sh[256];
    const int t = threadIdx.x;
    const int base = t * NB;
    int s = 0;
    for (int k = 0; k < NB; k++) s += wgcnt[base + k];
    sh[t] = s;
    __syncthreads();
    for (int off = 1; off < 256; off <<= 1) {
        int x = (t >= off) ? sh[t - off] : 0;
        __syncthreads();
        sh[t] += x;
        __syncthreads();
    }
    int run = sh[t] - s;
    for (int k = 0; k < NB; k++) {
        int v = wgcnt[base + k];
        binoff[base + k] = run;
        run += v;
    }
    if (t == 255) binoff[NB * NWG_A] = run;  // == E
}

__global__ __launch_bounds__(256) void bin_scatter_kernel(const int* __restrict__ src,
                                                          const int* __restrict__ dst,
                                                          const int* __restrict__ binoff,
                                                          unsigned* __restrict__ binned,
                                                          int E, int NB)
{
    __shared__ int cur[NBMAX];
    const int wg = blockIdx.x, tid = threadIdx.x;
    if (tid < NB) cur[tid] = binoff[tid * NWG_A + wg];
    __syncthreads();
    const int slab = (E + NWG_A - 1) / NWG_A;
    const int e0 = wg * slab;
    const int e1 = min(e0 + slab, E);
    for (int e = e0 + tid; e < e1; e += 256) {
        int d = dst[e];
        int b = d >> BSHIFT;
        unsigned rec = ((unsigned)(d & ((1 << BSHIFT) - 1)) << 17) | (unsigned)src[e];
        int p = atomicAdd(&cur[b], 1);
        binned[p] = rec;
    }
}

__global__ __launch_bounds__(256) void csr_build_kernel(const unsigned* __restrict__ binned,
                                                        const int* __restrict__ binoff,
                                                        int* __restrict__ csr,
                                                        int* __restrict__ offsets,
                                                        int* __restrict__ counts, int M)
{
    __shared__ int cnt[1 << BSHIFT];
    __shared__ int scn[1 << BSHIFT];
    __shared__ int sh[256];
    const int b = blockIdx.x, t = threadIdx.x;
    const int rs = binoff[b * NWG_A];
    const int re = binoff[(b + 1) * NWG_A];

    for (int j = t; j < (1 << BSHIFT); j += 256) cnt[j] = 0;
    __syncthreads();
    for (int i = rs + t; i < re; i += 256)
        atomicAdd(&cnt[binned[i] >> 17], 1);
    __syncthreads();

    const int base4 = t * 4;
    int v[4];
#pragma unroll
    for (int k = 0; k < 4; k++) v[k] = cnt[base4 + k];
    int s = v[0] + v[1] + v[2] + v[3];
    sh[t] = s;
    __syncthreads();
    for (int off = 1; off < 256; off <<= 1) {
        int x = (t >= off) ? sh[t - off] : 0;
        __syncthreads();
        sh[t] += x;
        __syncthreads();
    }
    int run = sh[t] - s;
#pragma unroll
    for (int k = 0; k < 4; k++) {
        scn[base4 + k] = run;
        run += v[k];
    }

    const int node0 = b << BSHIFT;
#pragma unroll
    for (int k = 0; k < 4; k++) {
        int j = base4 + k;
        int node = node0 + j;
        if (node < M) {
            counts[node] = v[k];
            offsets[node] = rs + scn[j];
        }
    }
    __syncthreads();

    for (int i = rs + t; i < re; i += 256) {
        unsigned r = binned[i];
        int p = atomicAdd(&scn[r >> 17], 1);
        csr[rs + p] = (int)(r & 0x1FFFFu);
    }
}

// ---------------- pull gather-max (unchanged from round 6) ----------------
__global__ __launch_bounds__(256) void gather_max_kernel(
    const u16x8* __restrict__ m16, const int* __restrict__ csr,
    const int* __restrict__ offsets, const int* __restrict__ counts,
    u16x8* __restrict__ agg16, int Nn)
{
    int wid = (blockIdx.x * 256 + threadIdx.x) >> 6;
    int lane = threadIdx.x & 63;
    if (wid >= Nn) return;
    const int g = lane >> 4, c = lane & 15;
    int start = offsets[wid];
    int deg = counts[wid];
    u16x8 acc = (u16x8){0, 0, 0, 0, 0, 0, 0, 0};
    for (int j0 = 0; j0 < deg; j0 += 64) {
        int nb = deg - j0;
        if (nb > 64) nb = 64;
        int sl = csr[start + j0 + (lane < nb ? lane : nb - 1)];
        for (int j = 0; j < nb; j += 4) {
            int jj = j + g;
            if (jj >= nb) jj = nb - 1;
            int s = __shfl(sl, jj);
            u16x8 v = m16[(size_t)s * 16 + c];
            acc = __builtin_elementwise_max(acc, v);
        }
    }
#pragma unroll
    for (int d = 16; d <= 32; d <<= 1) {
        int4 a = *(int4*)&acc;
        int4 t;
        t.x = __shfl_xor(a.x, d);
        t.y = __shfl_xor(a.y, d);
        t.z = __shfl_xor(a.z, d);
        t.w = __shfl_xor(a.w, d);
        acc = __builtin_elementwise_max(acc, *(u16x8*)&t);
    }
    if (g == 0) agg16[(size_t)wid * 16 + c] = acc;
}

// ---------------- generic MFMA GEMM: A direct from global, B-only LDS ----------------
// C = act( A0 @ B0^T [+ A1 @ B1^T] + bias ).  A0 f32 or bf16 per flag; A1 bf16.
template<int NT, bool RELU, int NPAIRS, bool A0F32, bool F32OUT>
__global__ __launch_bounds__(256, 4) void mfma_gemm_kernel(
    const void* __restrict__ A0v, const unsigned short* __restrict__ B0,
    const unsigned short* __restrict__ A1, const unsigned short* __restrict__ B1,
    const float* __restrict__ bias, void* __restrict__ Cout, int M, int Nout)
{
    constexpr int NR = NT * 16;
    __shared__ unsigned short Bs[NR * 136];
    __shared__ float BsF[NR];

    const int tid = threadIdx.x;
    const int w = tid >> 6, lane = tid & 63;
    const int q = lane >> 4, r16 = lane & 15;
    const int m0 = blockIdx.x * 128;

    if (tid < NR) BsF[tid] = (tid < Nout) ? bias[tid] : 0.f;

    int rowA[2];
#pragma unroll
    for (int rt = 0; rt < 2; rt++) {
        int r = m0 + w * 32 + rt * 16 + r16;
        rowA[rt] = r < M ? r : (M - 1);
    }

    f32x4 acc[2][NT];
#pragma unroll
    for (int i = 0; i < 2; i++)
#pragma unroll
        for (int j = 0; j < NT; j++) acc[i][j] = (f32x4){0.f, 0.f, 0.f, 0.f};

    for (int p = 0; p < NPAIRS; p++) {
        const unsigned short* __restrict__ B = p ? B1 : B0;
        if (p) __syncthreads();
        for (int j = tid; j < NR * 16; j += 256) {
            int row = j >> 4, cc = j & 15;
            uint4 v = *(const uint4*)&B[(size_t)row * 128 + cc * 8];
            *(uint4*)&Bs[row * 136 + cc * 8] = v;
        }
        __syncthreads();

#pragma unroll
        for (int k0 = 0; k0 < 128; k0 += 32) {
            bf16x8 af[2];
#pragma unroll
            for (int rt = 0; rt < 2; rt++) {
                if (p == 0 && A0F32)
                    af[rt] = loadA_f32((const float*)A0v, (size_t)rowA[rt] * 128 + k0 + q * 8);
                else {
                    const unsigned short* Ab = p ? A1 : (const unsigned short*)A0v;
                    af[rt] = *(const bf16x8*)&Ab[(size_t)rowA[rt] * 128 + k0 + q * 8];
                }
            }
#pragma unroll
            for (int ct = 0; ct < NT; ct++) {
                bf16x8 bfr = *(const bf16x8*)&Bs[(ct * 16 + r16) * 136 + k0 + q * 8];
#pragma unroll
                for (int rt = 0; rt < 2; rt++)
                    acc[rt][ct] = __builtin_amdgcn_mfma_f32_16x16x32_bf16(
                        af[rt], bfr, acc[rt][ct], 0, 0, 0);
            }
        }
    }

#pragma unroll
    for (int rt = 0; rt < 2; rt++) {
#pragma unroll
        for (int ct = 0; ct < NT; ct++) {
            int col = ct * 16 + r16;
#pragma unroll
            for (int r = 0; r < 4; r++) {
                int grow = m0 + w * 32 + rt * 16 + q * 4 + r;
                float v = acc[rt][ct][r] + BsF[col];
                if (RELU) v = fmaxf(v, 0.f);
                if (grow < M && col < Nout) {
                    if (F32OUT)
                        ((float*)Cout)[(size_t)grow * Nout + col] = v;
                    else
                        ((unsigned short*)Cout)[(size_t)grow * Nout + col] = f2bf(v);
                }
            }
        }
    }
}

// ---------------- sn_pool: h1 = relu(in@sw1^T + agg@nw1^T + b); m2 = relu(h1@pw2^T + b2) ----------------
// Chained GEMM: h1 tile kept in LDS (full K=128 per 128-row tile) feeds the
// pool2 MFMA pass in the same kernel. LDS ~70 KB -> 2 blocks/CU (MFMA-bound,
// tolerates low occupancy per r7 evidence).
__global__ __launch_bounds__(256, 2) void sn_pool_kernel(
    const float* __restrict__ A0f, const unsigned short* __restrict__ B0,
    const unsigned short* __restrict__ A1, const unsigned short* __restrict__ B1,
    const float* __restrict__ bias_sn, const unsigned short* __restrict__ Bp,
    const float* __restrict__ bias_p, unsigned short* __restrict__ h1out,
    unsigned short* __restrict__ m2out, int M)
{
    __shared__ unsigned short Bs[128 * 136];
    __shared__ unsigned short H[128 * 136];
    __shared__ float BsF[128];

    const int tid = threadIdx.x;
    const int w = tid >> 6, lane = tid & 63;
    const int q = lane >> 4, r16 = lane & 15;
    const int m0 = blockIdx.x * 128;

    if (tid < 128) BsF[tid] = bias_sn[tid];

    int rowA[2];
#pragma unroll
    for (int rt = 0; rt < 2; rt++) {
        int r = m0 + w * 32 + rt * 16 + r16;
        rowA[rt] = r < M ? r : (M - 1);
    }

    f32x4 acc[2][8];
#pragma unroll
    for (int i = 0; i < 2; i++)
#pragma unroll
        for (int j = 0; j < 8; j++) acc[i][j] = (f32x4){0.f, 0.f, 0.f, 0.f};

    // pair 0: self — A0 f32 from global (on-the-fly bf16 convert), Bs=B0
    for (int j = tid; j < 2048; j += 256) {
        int row = j >> 4, cc = j & 15;
        *(uint4*)&Bs[row * 136 + cc * 8] = *(const uint4*)&B0[(size_t)row * 128 + cc * 8];
    }
    __syncthreads();
#pragma unroll
    for (int k0 = 0; k0 < 128; k0 += 32) {
        bf16x8 af[2];
#pragma unroll
        for (int rt = 0; rt < 2; rt++)
            af[rt] = loadA_f32(A0f, (size_t)rowA[rt] * 128 + k0 + q * 8);
#pragma unroll
        for (int ct = 0; ct < 8; ct++) {
            bf16x8 bfr = *(const bf16x8*)&Bs[(ct * 16 + r16) * 136 + k0 + q * 8];
#pragma unroll
            for (int rt = 0; rt < 2; rt++)
                acc[rt][ct] = __builtin_amdgcn_mfma_f32_16x16x32_bf16(
                    af[rt], bfr, acc[rt][ct], 0, 0, 0);
        }
    }
    __syncthreads();

    // pair 1: neigh — A1=agg bf16 from global, Bs=B1
    for (int j = tid; j < 2048; j += 256) {
        int row = j >> 4, cc = j & 15;
        *(uint4*)&Bs[row * 136 + cc * 8] = *(const uint4*)&B1[(size_t)row * 128 + cc * 8];
    }
    __syncthreads();
#pragma unroll
    for (int k0 = 0; k0 < 128; k0 += 32) {
        bf16x8 af[2];
#pragma unroll
        for (int rt = 0; rt < 2; rt++)
            af[rt] = *(const bf16x8*)&A1[(size_t)rowA[rt] * 128 + k0 + q * 8];
#pragma unroll
        for (int ct = 0; ct < 8; ct++) {
            bf16x8 bfr = *(const bf16x8*)&Bs[(ct * 16 + r16) * 136 + k0 + q * 8];
#pragma unroll
            for (int rt = 0; rt < 2; rt++)
                acc[rt][ct] = __builtin_amdgcn_mfma_f32_16x16x32_bf16(
                    af[rt], bfr, acc[rt][ct], 0, 0, 0);
        }
    }

    // epilogue 1: h1 = relu(acc + b_sn); write global + LDS tile
#pragma unroll
    for (int rt = 0; rt < 2; rt++) {
#pragma unroll
        for (int ct = 0; ct < 8; ct++) {
            int col = ct * 16 + r16;
#pragma unroll
            for (int r = 0; r < 4; r++) {
                int lr = w * 32 + rt * 16 + q * 4 + r;
                int grow = m0 + lr;
                float v = fmaxf(acc[rt][ct][r] + BsF[col], 0.f);
                unsigned short hb = f2bf(v);
                H[lr * 136 + col] = hb;
                if (grow < M) h1out[(size_t)grow * 128 + col] = hb;
            }
        }
    }
    __syncthreads();                       // H complete; Bs consumed

    // pass 2: m2 = relu(H @ pw2^T + b_p)
    for (int j = tid; j < 2048; j += 256) {
        int row = j >> 4, cc = j & 15;
        *(uint4*)&Bs[row * 136 + cc * 8] = *(const uint4*)&Bp[(size_t)row * 128 + cc * 8];
    }
    if (tid < 128) BsF[tid] = bias_p[tid];
    __syncthreads();

#pragma unroll
    for (int i = 0; i < 2; i++)
#pragma unroll
        for (int j = 0; j < 8; j++) acc[i][j] = (f32x4){0.f, 0.f, 0.f, 0.f};

#pragma unroll
    for (int k0 = 0; k0 < 128; k0 += 32) {
        bf16x8 af[2];
#pragma unroll
        for (int rt = 0; rt < 2; rt++)
            af[rt] = *(const bf16x8*)&H[(w * 32 + rt * 16 + r16) * 136 + k0 + q * 8];
#pragma unroll
        for (int ct = 0; ct < 8; ct++) {
            bf16x8 bfr = *(const bf16x8*)&Bs[(ct * 16 + r16) * 136 + k0 + q * 8];
#pragma unroll
            for (int rt = 0; rt < 2; rt++)
                acc[rt][ct] = __builtin_amdgcn_mfma_f32_16x16x32_bf16(
                    af[rt], bfr, acc[rt][ct], 0, 0, 0);
        }
    }

#pragma unroll
    for (int rt = 0; rt < 2; rt++) {
#pragma unroll
        for (int ct = 0; ct < 8; ct++) {
            int col = ct * 16 + r16;
#pragma unroll
            for (int r = 0; r < 4; r++) {
                int grow = m0 + w * 32 + rt * 16 + q * 4 + r;
                if (grow < M) {
                    float v = fmaxf(acc[rt][ct][r] + BsF[col], 0.f);
                    m2out[(size_t)grow * 128 + col] = f2bf(v);
                }
            }
        }
    }
}

extern "C" void kernel_launch(void* const* d_in, const int* in_sizes, int n_in,
                              void* d_out, int out_size, void* d_ws, size_t ws_size,
                              hipStream_t stream)
{
    const float* in_feat = (const float*)d_in[0];
    const int*   src     = (const int*)d_in[1];
    const int*   dst     = (const int*)d_in[2];
    const float* pw1 = (const float*)d_in[3];  const float* pb1 = (const float*)d_in[4];
    const float* sw1 = (const float*)d_in[5];  const float* sb1 = (const float*)d_in[6];
    const float* nw1 = (const float*)d_in[7];  const float* nb1 = (const float*)d_in[8];
    const float* pw2 = (const float*)d_in[9];  const float* pb2 = (const float*)d_in[10];
    const float* sw2 = (const float*)d_in[11]; const float* sb2 = (const float*)d_in[12];
    const float* nw2 = (const float*)d_in[13]; const float* nb2 = (const float*)d_in[14];
    float* out = (float*)d_out;

    const int M = in_sizes[0] / N_FEAT;   // 100000 nodes
    const int E = in_sizes[1];            // 1600000 edges
    const int NB = (M + (1 << BSHIFT) - 1) >> BSHIFT;   // 98 buckets

    // ---- workspace layout (256B-aligned regions) ----
    char* base = (char*)d_ws;
    size_t off = 0;
    auto alloc = [&](size_t bytes) { char* p = base + off; off = (off + bytes + 255) & ~(size_t)255; return p; };
    unsigned short* wb_p1 = (unsigned short*)alloc(16384 * 2);
    unsigned short* wb_s1 = (unsigned short*)alloc(16384 * 2);
    unsigned short* wb_n1 = (unsigned short*)alloc(16384 * 2);
    unsigned short* wb_p2 = (unsigned short*)alloc(16384 * 2);
    unsigned short* wb_s2 = (unsigned short*)alloc(6144 * 2);
    unsigned short* wb_n2 = (unsigned short*)alloc(6144 * 2);
    float* b_sn1 = (float*)alloc(128 * 4);
    float* b_sn2 = (float*)alloc(64 * 4);
    unsigned short* mb   = (unsigned short*)alloc((size_t)M * 128 * 2);
    unsigned short* agg  = (unsigned short*)alloc((size_t)M * 128 * 2);
    unsigned short* h1   = (unsigned short*)alloc((size_t)M * 128 * 2);
    int* counts  = (int*)alloc((size_t)M * 4);
    int* offsets = (int*)alloc((size_t)M * 4);
    int* wgcnt   = (int*)alloc((size_t)NB * NWG_A * 4);
    int* binoff  = (int*)alloc(((size_t)NB * NWG_A + 1) * 4);
    unsigned* binned = (unsigned*)alloc((size_t)E * 4);
    int* csr     = (int*)alloc((size_t)E * 4);

    const int gemm_grid = (M + 127) / 128;
    const int gather_grid = (M * 64 + 255) / 256;       // one wave per node

    // prep + bin_count merged (blocks [0,256) = bin_count, [256,320) = prep)
    prep_bin_kernel<<<NWG_A + 64, 256, 0, stream>>>(
        pw1, sw1, nw1, pw2, sw2, nw2, sb1, nb1, sb2, nb2,
        wb_p1, wb_s1, wb_n1, wb_p2, wb_s2, wb_n2, b_sn1, b_sn2,
        dst, wgcnt, E, NB);
    bin_scan_kernel<<<1, 256, 0, stream>>>(wgcnt, binoff, NB);
    bin_scatter_kernel<<<NWG_A, 256, 0, stream>>>(src, dst, binoff, binned, E, NB);
    csr_build_kernel<<<NB, 256, 0, stream>>>(binned, binoff, csr, offsets, counts, M);

    // ---- Layer 1 ----
    mfma_gemm_kernel<8, true, 1, true, false><<<gemm_grid, 256, 0, stream>>>(
        in_feat, wb_p1, nullptr, nullptr, pb1, mb, M, 128);
    gather_max_kernel<<<gather_grid, 256, 0, stream>>>(
        (const u16x8*)mb, csr, offsets, counts, (u16x8*)agg, M);
    sn_pool_kernel<<<gemm_grid, 256, 0, stream>>>(
        in_feat, wb_s1, agg, wb_n1, b_sn1, wb_p2, pb2, h1, mb, M);

    // ---- Layer 2 ----
    gather_max_kernel<<<gather_grid, 256, 0, stream>>>(
        (const u16x8*)mb, csr, offsets, counts, (u16x8*)agg, M);
    mfma_gemm_kernel<3, false, 2, false, true><<<gemm_grid, 256, 0, stream>>>(
        h1, wb_s2, agg, wb_n2, b_sn2, out, M, 40);
}

// Round 9
// 391.576 us; speedup vs baseline: 1.4525x; 1.0058x over previous
//
#include <hip/hip_runtime.h>

// GraphSAGE (pool aggregator, 2 layers) on MI355X.
// Round 9: shrink the serialized CSR section (gathers are at their fabric
// service floor; r7 proved they must stay standalone at high occupancy).
//   - scatter_pool: bin_scatter (256 blks) + pool1 GEMM (782 blks) merged in
//     one dispatch (independent work; scatter hides under the GEMM)
//   - csr_build at 1024 thr: bucket=1024 nodes -> thread t owns node t;
//     hist/scan/scatter 4x more parallel (was 98 blks x 256 thr = 38% CUs)
//   - bin_scan at 1024 thr
//   - nontemporal stores for agg + binned (streamed-once; keep m rows in L2)
// Gather, sn_pool, final GEMM unchanged from round 8.

#define N_FEAT 128
#define NWG_A 256
#define BSHIFT 10            // 1024 nodes per bucket
#define NBMAX 128

typedef __attribute__((ext_vector_type(8))) short bf16x8;            // 8 bf16 = 4 VGPRs
typedef __attribute__((ext_vector_type(8))) unsigned short u16x8;    // 16 B
typedef __attribute__((ext_vector_type(4))) float f32x4;

static __device__ __forceinline__ unsigned short f2bf(float f) {
    unsigned u = __float_as_uint(f);
    unsigned r = (u + 0x7fffu + ((u >> 16) & 1u)) >> 16;   // RNE
    return (unsigned short)r;
}

static __device__ __forceinline__ bf16x8 loadA_f32(const float* __restrict__ A, size_t idx) {
    float4 a = *(const float4*)&A[idx];
    float4 b = *(const float4*)&A[idx + 4];
    bf16x8 r;
    r[0] = (short)f2bf(a.x); r[1] = (short)f2bf(a.y);
    r[2] = (short)f2bf(a.z); r[3] = (short)f2bf(a.w);
    r[4] = (short)f2bf(b.x); r[5] = (short)f2bf(b.y);
    r[6] = (short)f2bf(b.z); r[7] = (short)f2bf(b.w);
    return r;
}

// ---------------- prep (weights->bf16, fused biases) + bin_count merged ----------------
__global__ __launch_bounds__(256) void prep_bin_kernel(
    const float* __restrict__ pw1, const float* __restrict__ sw1,
    const float* __restrict__ nw1, const float* __restrict__ pw2,
    const float* __restrict__ sw2, const float* __restrict__ nw2,
    const float* __restrict__ sb1, const float* __restrict__ nb1,
    const float* __restrict__ sb2, const float* __restrict__ nb2,
    unsigned short* __restrict__ wb_p1, unsigned short* __restrict__ wb_s1,
    unsigned short* __restrict__ wb_n1, unsigned short* __restrict__ wb_p2,
    unsigned short* __restrict__ wb_s2, unsigned short* __restrict__ wb_n2,
    float* __restrict__ b_sn1, float* __restrict__ b_sn2,
    const int* __restrict__ dst, int* __restrict__ wgcnt, int E, int NB)
{
    __shared__ int cnt[NBMAX];
    if (blockIdx.x < NWG_A) {
        const int wg = blockIdx.x, tid = threadIdx.x;
        if (tid < NB) cnt[tid] = 0;
        __syncthreads();
        const int slab = (E + NWG_A - 1) / NWG_A;
        const int e0 = wg * slab;
        const int e1 = min(e0 + slab, E);
        for (int e = e0 + tid; e < e1; e += 256)
            atomicAdd(&cnt[dst[e] >> BSHIFT], 1);
        __syncthreads();
        if (tid < NB) wgcnt[tid * NWG_A + wg] = cnt[tid];
    } else {
        int t = (blockIdx.x - NWG_A) * 256 + threadIdx.x;
        if (t < 16384) {
            wb_p1[t] = f2bf(pw1[t]);
            wb_s1[t] = f2bf(sw1[t]);
            wb_n1[t] = f2bf(nw1[t]);
            wb_p2[t] = f2bf(pw2[t]);
        }
        if (t < 6144) {                   // 48x128, rows 40..47 zero-padded
            int row = t >> 7;
            wb_s2[t] = (row < 40) ? f2bf(sw2[t]) : 0;
            wb_n2[t] = (row < 40) ? f2bf(nw2[t]) : 0;
        }
        if (t < 128) b_sn1[t] = sb1[t] + nb1[t];
        if (t < 64)  b_sn2[t] = (t < 40) ? (sb2[t] + nb2[t]) : 0.f;
    }
}

// ---------------- bin_scan: 1024-thread exclusive scan of NB*NWG_A counts ----------------
__global__ __launch_bounds__(1024) void bin_scan_kernel(const int* __restrict__ wgcnt,
                                                        int* __restrict__ binoff, int NB)
{
    __shared__ int sh[1024];
    const int t = threadIdx.x;
    const int total = NB * NWG_A;
    const int chunk = (total + 1023) / 1024;
    const int b0 = t * chunk;
    const int b1 = min(b0 + chunk, total);
    int s = 0;
    for (int k = b0; k < b1; k++) s += wgcnt[k];
    sh[t] = s;
    __syncthreads();
    for (int off = 1; off < 1024; off <<= 1) {
        int x = (t >= off) ? sh[t - off] : 0;
        __syncthreads();
        sh[t] += x;
        __syncthreads();
    }
    int run = sh[t] - s;
    for (int k = b0; k < b1; k++) {
        int v = wgcnt[k];
        binoff[k] = run;
        run += v;
    }
    if (t == 1023) binoff[total] = sh[1023];   // == E
}

// ---------------- scatter_pool: bin_scatter (blocks 0..255) + pool1 GEMM ----------------
// mb = relu(in_feat @ pw1^T + pb1), bf16 out. Independent of the scatter half.
__global__ __launch_bounds__(256, 4) void scatter_pool_kernel(
    const int* __restrict__ src, const int* __restrict__ dst,
    const int* __restrict__ binoff, unsigned* __restrict__ binned, int E, int NB,
    const float* __restrict__ A0f, const unsigned short* __restrict__ B0,
    const float* __restrict__ bias, unsigned short* __restrict__ Cout, int M)
{
    __shared__ int cur[NBMAX];
    __shared__ unsigned short Bs[128 * 136];
    __shared__ float BsF[128];

    if (blockIdx.x < NWG_A) {
        // ---- bin_scatter body ----
        const int wg = blockIdx.x, tid = threadIdx.x;
        if (tid < NB) cur[tid] = binoff[tid * NWG_A + wg];
        __syncthreads();
        const int slab = (E + NWG_A - 1) / NWG_A;
        const int e0 = wg * slab;
        const int e1 = min(e0 + slab, E);
        for (int e = e0 + tid; e < e1; e += 256) {
            int d = dst[e];
            int b = d >> BSHIFT;
            unsigned rec = ((unsigned)(d & ((1 << BSHIFT) - 1)) << 17) | (unsigned)src[e];
            int p = atomicAdd(&cur[b], 1);
            __builtin_nontemporal_store(rec, &binned[p]);
        }
        return;
    }

    // ---- pool1 GEMM body ----
    const int tid = threadIdx.x;
    const int w = tid >> 6, lane = tid & 63;
    const int q = lane >> 4, r16 = lane & 15;
    const int m0 = (blockIdx.x - NWG_A) * 128;

    if (tid < 128) BsF[tid] = bias[tid];

    int rowA[2];
#pragma unroll
    for (int rt = 0; rt < 2; rt++) {
        int r = m0 + w * 32 + rt * 16 + r16;
        rowA[rt] = r < M ? r : (M - 1);
    }

    f32x4 acc[2][8];
#pragma unroll
    for (int i = 0; i < 2; i++)
#pragma unroll
        for (int j = 0; j < 8; j++) acc[i][j] = (f32x4){0.f, 0.f, 0.f, 0.f};

    for (int j = tid; j < 2048; j += 256) {
        int row = j >> 4, cc = j & 15;
        *(uint4*)&Bs[row * 136 + cc * 8] = *(const uint4*)&B0[(size_t)row * 128 + cc * 8];
    }
    __syncthreads();

#pragma unroll
    for (int k0 = 0; k0 < 128; k0 += 32) {
        bf16x8 af[2];
#pragma unroll
        for (int rt = 0; rt < 2; rt++)
            af[rt] = loadA_f32(A0f, (size_t)rowA[rt] * 128 + k0 + q * 8);
#pragma unroll
        for (int ct = 0; ct < 8; ct++) {
            bf16x8 bfr = *(const bf16x8*)&Bs[(ct * 16 + r16) * 136 + k0 + q * 8];
#pragma unroll
            for (int rt = 0; rt < 2; rt++)
                acc[rt][ct] = __builtin_amdgcn_mfma_f32_16x16x32_bf16(
                    af[rt], bfr, acc[rt][ct], 0, 0, 0);
        }
    }

#pragma unroll
    for (int rt = 0; rt < 2; rt++) {
#pragma unroll
        for (int ct = 0; ct < 8; ct++) {
            int col = ct * 16 + r16;
#pragma unroll
            for (int r = 0; r < 4; r++) {
                int grow = m0 + w * 32 + rt * 16 + q * 4 + r;
                if (grow < M) {
                    float v = fmaxf(acc[rt][ct][r] + BsF[col], 0.f);
                    Cout[(size_t)grow * 128 + col] = f2bf(v);
                }
            }
        }
    }
}

// ---------------- csr_build: 1024 threads, thread t owns node t of the bucket ----------------
__global__ __launch_bounds__(1024) void csr_build_kernel(const unsigned* __restrict__ binned,
                                                         const int* __restrict__ binoff,
                                                         int* __restrict__ csr,
                                                         int* __restrict__ offsets,
                                                         int* __restrict__ counts, int M)
{
    __shared__ int cnt[1 << BSHIFT];
    __shared__ int pref[1 << BSHIFT];
    const int b = blockIdx.x, t = threadIdx.x;
    const int rs = binoff[b * NWG_A];
    const int re = binoff[(b + 1) * NWG_A];

    cnt[t] = 0;
    __syncthreads();
    for (int i = rs + t; i < re; i += 1024)
        atomicAdd(&cnt[binned[i] >> 17], 1);
    __syncthreads();

    int v = cnt[t];
    pref[t] = v;
    __syncthreads();
    for (int off = 1; off < 1024; off <<= 1) {
        int x = (t >= off) ? pref[t - off] : 0;
        __syncthreads();
        pref[t] += x;
        __syncthreads();
    }
    int excl = pref[t] - v;

    int node = (b << BSHIFT) + t;
    if (node < M) {
        counts[node] = v;
        offsets[node] = rs + excl;
    }
    cnt[t] = excl;                       // reuse as cursor
    __syncthreads();

    for (int i = rs + t; i < re; i += 1024) {
        unsigned r = binned[i];
        int p = atomicAdd(&cnt[r >> 17], 1);
        csr[rs + p] = (int)(r & 0x1FFFFu);
    }
}

// ---------------- pull gather-max (r6 structure + NT agg store) ----------------
__global__ __launch_bounds__(256) void gather_max_kernel(
    const u16x8* __restrict__ m16, const int* __restrict__ csr,
    const int* __restrict__ offsets, const int* __restrict__ counts,
    u16x8* __restrict__ agg16, int Nn)
{
    int wid = (blockIdx.x * 256 + threadIdx.x) >> 6;
    int lane = threadIdx.x & 63;
    if (wid >= Nn) return;
    const int g = lane >> 4, c = lane & 15;
    int start = offsets[wid];
    int deg = counts[wid];
    u16x8 acc = (u16x8){0, 0, 0, 0, 0, 0, 0, 0};
    for (int j0 = 0; j0 < deg; j0 += 64) {
        int nb = deg - j0;
        if (nb > 64) nb = 64;
        int sl = csr[start + j0 + (lane < nb ? lane : nb - 1)];
        for (int j = 0; j < nb; j += 4) {
            int jj = j + g;
            if (jj >= nb) jj = nb - 1;
            int s = __shfl(sl, jj);
            u16x8 v = m16[(size_t)s * 16 + c];
            acc = __builtin_elementwise_max(acc, v);
        }
    }
#pragma unroll
    for (int d = 16; d <= 32; d <<= 1) {
        int4 a = *(int4*)&acc;
        int4 t;
        t.x = __shfl_xor(a.x, d);
        t.y = __shfl_xor(a.y, d);
        t.z = __shfl_xor(a.z, d);
        t.w = __shfl_xor(a.w, d);
        acc = __builtin_elementwise_max(acc, *(u16x8*)&t);
    }
    if (g == 0) __builtin_nontemporal_store(acc, &agg16[(size_t)wid * 16 + c]);
}

// ---------------- generic MFMA GEMM (final layer): A direct from global, B-only LDS ----------------
template<int NT, bool RELU, int NPAIRS, bool F32OUT>
__global__ __launch_bounds__(256, 4) void mfma_gemm_kernel(
    const unsigned short* __restrict__ A0, const unsigned short* __restrict__ B0,
    const unsigned short* __restrict__ A1, const unsigned short* __restrict__ B1,
    const float* __restrict__ bias, void* __restrict__ Cout, int M, int Nout)
{
    constexpr int NR = NT * 16;
    __shared__ unsigned short Bs[NR * 136];
    __shared__ float BsF[NR];

    const int tid = threadIdx.x;
    const int w = tid >> 6, lane = tid & 63;
    const int q = lane >> 4, r16 = lane & 15;
    const int m0 = blockIdx.x * 128;

    if (tid < NR) BsF[tid] = (tid < Nout) ? bias[tid] : 0.f;

    int rowA[2];
#pragma unroll
    for (int rt = 0; rt < 2; rt++) {
        int r = m0 + w * 32 + rt * 16 + r16;
        rowA[rt] = r < M ? r : (M - 1);
    }

    f32x4 acc[2][NT];
#pragma unroll
    for (int i = 0; i < 2; i++)
#pragma unroll
        for (int j = 0; j < NT; j++) acc[i][j] = (f32x4){0.f, 0.f, 0.f, 0.f};

    for (int p = 0; p < NPAIRS; p++) {
        const unsigned short* __restrict__ B = p ? B1 : B0;
        const unsigned short* __restrict__ A = p ? A1 : A0;
        if (p) __syncthreads();
        for (int j = tid; j < NR * 16; j += 256) {
            int row = j >> 4, cc = j & 15;
            uint4 v = *(const uint4*)&B[(size_t)row * 128 + cc * 8];
            *(uint4*)&Bs[row * 136 + cc * 8] = v;
        }
        __syncthreads();

#pragma unroll
        for (int k0 = 0; k0 < 128; k0 += 32) {
            bf16x8 af[2];
#pragma unroll
            for (int rt = 0; rt < 2; rt++)
                af[rt] = *(const bf16x8*)&A[(size_t)rowA[rt] * 128 + k0 + q * 8];
#pragma unroll
            for (int ct = 0; ct < NT; ct++) {
                bf16x8 bfr = *(const bf16x8*)&Bs[(ct * 16 + r16) * 136 + k0 + q * 8];
#pragma unroll
                for (int rt = 0; rt < 2; rt++)
                    acc[rt][ct] = __builtin_amdgcn_mfma_f32_16x16x32_bf16(
                        af[rt], bfr, acc[rt][ct], 0, 0, 0);
            }
        }
    }

#pragma unroll
    for (int rt = 0; rt < 2; rt++) {
#pragma unroll
        for (int ct = 0; ct < NT; ct++) {
            int col = ct * 16 + r16;
#pragma unroll
            for (int r = 0; r < 4; r++) {
                int grow = m0 + w * 32 + rt * 16 + q * 4 + r;
                float v = acc[rt][ct][r] + BsF[col];
                if (RELU) v = fmaxf(v, 0.f);
                if (grow < M && col < Nout) {
                    if (F32OUT)
                        ((float*)Cout)[(size_t)grow * Nout + col] = v;
                    else
                        ((unsigned short*)Cout)[(size_t)grow * Nout + col] = f2bf(v);
                }
            }
        }
    }
}

// ---------------- sn_pool (unchanged from round 8) ----------------
__global__ __launch_bounds__(256, 2) void sn_pool_kernel(
    const float* __restrict__ A0f, const unsigned short* __restrict__ B0,
    const unsigned short* __restrict__ A1, const unsigned short* __restrict__ B1,
    const float* __restrict__ bias_sn, const unsigned short* __restrict__ Bp,
    const float* __restrict__ bias_p, unsigned short* __restrict__ h1out,
    unsigned short* __restrict__ m2out, int M)
{
    __shared__ unsigned short Bs[128 * 136];
    __shared__ unsigned short H[128 * 136];
    __shared__ float BsF[128];

    const int tid = threadIdx.x;
    const int w = tid >> 6, lane = tid & 63;
    const int q = lane >> 4, r16 = lane & 15;
    const int m0 = blockIdx.x * 128;

    if (tid < 128) BsF[tid] = bias_sn[tid];

    int rowA[2];
#pragma unroll
    for (int rt = 0; rt < 2; rt++) {
        int r = m0 + w * 32 + rt * 16 + r16;
        rowA[rt] = r < M ? r : (M - 1);
    }

    f32x4 acc[2][8];
#pragma unroll
    for (int i = 0; i < 2; i++)
#pragma unroll
        for (int j = 0; j < 8; j++) acc[i][j] = (f32x4){0.f, 0.f, 0.f, 0.f};

    // pair 0: self — A0 f32 from global, Bs=B0
    for (int j = tid; j < 2048; j += 256) {
        int row = j >> 4, cc = j & 15;
        *(uint4*)&Bs[row * 136 + cc * 8] = *(const uint4*)&B0[(size_t)row * 128 + cc * 8];
    }
    __syncthreads();
#pragma unroll
    for (int k0 = 0; k0 < 128; k0 += 32) {
        bf16x8 af[2];
#pragma unroll
        for (int rt = 0; rt < 2; rt++)
            af[rt] = loadA_f32(A0f, (size_t)rowA[rt] * 128 + k0 + q * 8);
#pragma unroll
        for (int ct = 0; ct < 8; ct++) {
            bf16x8 bfr = *(const bf16x8*)&Bs[(ct * 16 + r16) * 136 + k0 + q * 8];
#pragma unroll
            for (int rt = 0; rt < 2; rt++)
                acc[rt][ct] = __builtin_amdgcn_mfma_f32_16x16x32_bf16(
                    af[rt], bfr, acc[rt][ct], 0, 0, 0);
        }
    }
    __syncthreads();

    // pair 1: neigh — A1=agg bf16 from global, Bs=B1
    for (int j = tid; j < 2048; j += 256) {
        int row = j >> 4, cc = j & 15;
        *(uint4*)&Bs[row * 136 + cc * 8] = *(const uint4*)&B1[(size_t)row * 128 + cc * 8];
    }
    __syncthreads();
#pragma unroll
    for (int k0 = 0; k0 < 128; k0 += 32) {
        bf16x8 af[2];
#pragma unroll
        for (int rt = 0; rt < 2; rt++)
            af[rt] = *(const bf16x8*)&A1[(size_t)rowA[rt] * 128 + k0 + q * 8];
#pragma unroll
        for (int ct = 0; ct < 8; ct++) {
            bf16x8 bfr = *(const bf16x8*)&Bs[(ct * 16 + r16) * 136 + k0 + q * 8];
#pragma unroll
            for (int rt = 0; rt < 2; rt++)
                acc[rt][ct] = __builtin_amdgcn_mfma_f32_16x16x32_bf16(
                    af[rt], bfr, acc[rt][ct], 0, 0, 0);
        }
    }

    // epilogue 1: h1 = relu(acc + b_sn); write global + LDS tile
#pragma unroll
    for (int rt = 0; rt < 2; rt++) {
#pragma unroll
        for (int ct = 0; ct < 8; ct++) {
            int col = ct * 16 + r16;
#pragma unroll
            for (int r = 0; r < 4; r++) {
                int lr = w * 32 + rt * 16 + q * 4 + r;
                int grow = m0 + lr;
                float v = fmaxf(acc[rt][ct][r] + BsF[col], 0.f);
                unsigned short hb = f2bf(v);
                H[lr * 136 + col] = hb;
                if (grow < M) h1out[(size_t)grow * 128 + col] = hb;
            }
        }
    }
    __syncthreads();

    // pass 2: m2 = relu(H @ pw2^T + b_p)
    for (int j = tid; j < 2048; j += 256) {
        int row = j >> 4, cc = j & 15;
        *(uint4*)&Bs[row * 136 + cc * 8] = *(const uint4*)&Bp[(size_t)row * 128 + cc * 8];
    }
    if (tid < 128) BsF[tid] = bias_p[tid];
    __syncthreads();

#pragma unroll
    for (int i = 0; i < 2; i++)
#pragma unroll
        for (int j = 0; j < 8; j++) acc[i][j] = (f32x4){0.f, 0.f, 0.f, 0.f};

#pragma unroll
    for (int k0 = 0; k0 < 128; k0 += 32) {
        bf16x8 af[2];
#pragma unroll
        for (int rt = 0; rt < 2; rt++)
            af[rt] = *(const bf16x8*)&H[(w * 32 + rt * 16 + r16) * 136 + k0 + q * 8];
#pragma unroll
        for (int ct = 0; ct < 8; ct++) {
            bf16x8 bfr = *(const bf16x8*)&Bs[(ct * 16 + r16) * 136 + k0 + q * 8];
#pragma unroll
            for (int rt = 0; rt < 2; rt++)
                acc[rt][ct] = __builtin_amdgcn_mfma_f32_16x16x32_bf16(
                    af[rt], bfr, acc[rt][ct], 0, 0, 0);
        }
    }

#pragma unroll
    for (int rt = 0; rt < 2; rt++) {
#pragma unroll
        for (int ct = 0; ct < 8; ct++) {
            int col = ct * 16 + r16;
#pragma unroll
            for (int r = 0; r < 4; r++) {
                int grow = m0 + w * 32 + rt * 16 + q * 4 + r;
                if (grow < M) {
                    float v = fmaxf(acc[rt][ct][r] + BsF[col], 0.f);
                    m2out[(size_t)grow * 128 + col] = f2bf(v);
                }
            }
        }
    }
}

extern "C" void kernel_launch(void* const* d_in, const int* in_sizes, int n_in,
                              void* d_out, int out_size, void* d_ws, size_t ws_size,
                              hipStream_t stream)
{
    const float* in_feat = (const float*)d_in[0];
    const int*   src     = (const int*)d_in[1];
    const int*   dst     = (const int*)d_in[2];
    const float* pw1 = (const float*)d_in[3];  const float* pb1 = (const float*)d_in[4];
    const float* sw1 = (const float*)d_in[5];  const float* sb1 = (const float*)d_in[6];
    const float* nw1 = (const float*)d_in[7];  const float* nb1 = (const float*)d_in[8];
    const float* pw2 = (const float*)d_in[9];  const float* pb2 = (const float*)d_in[10];
    const float* sw2 = (const float*)d_in[11]; const float* sb2 = (const float*)d_in[12];
    const float* nw2 = (const float*)d_in[13]; const float* nb2 = (const float*)d_in[14];
    float* out = (float*)d_out;

    const int M = in_sizes[0] / N_FEAT;   // 100000 nodes
    const int E = in_sizes[1];            // 1600000 edges
    const int NB = (M + (1 << BSHIFT) - 1) >> BSHIFT;   // 98 buckets

    // ---- workspace layout (256B-aligned regions) ----
    char* base = (char*)d_ws;
    size_t off = 0;
    auto alloc = [&](size_t bytes) { char* p = base + off; off = (off + bytes + 255) & ~(size_t)255; return p; };
    unsigned short* wb_p1 = (unsigned short*)alloc(16384 * 2);
    unsigned short* wb_s1 = (unsigned short*)alloc(16384 * 2);
    unsigned short* wb_n1 = (unsigned short*)alloc(16384 * 2);
    unsigned short* wb_p2 = (unsigned short*)alloc(16384 * 2);
    unsigned short* wb_s2 = (unsigned short*)alloc(6144 * 2);
    unsigned short* wb_n2 = (unsigned short*)alloc(6144 * 2);
    float* b_sn1 = (float*)alloc(128 * 4);
    float* b_sn2 = (float*)alloc(64 * 4);
    unsigned short* mb   = (unsigned short*)alloc((size_t)M * 128 * 2);
    unsigned short* agg  = (unsigned short*)alloc((size_t)M * 128 * 2);
    unsigned short* h1   = (unsigned short*)alloc((size_t)M * 128 * 2);
    int* counts  = (int*)alloc((size_t)M * 4);
    int* offsets = (int*)alloc((size_t)M * 4);
    int* wgcnt   = (int*)alloc((size_t)NB * NWG_A * 4);
    int* binoff  = (int*)alloc(((size_t)NB * NWG_A + 1) * 4);
    unsigned* binned = (unsigned*)alloc((size_t)E * 4);
    int* csr     = (int*)alloc((size_t)E * 4);

    const int gemm_grid = (M + 127) / 128;              // 782
    const int gather_grid = (M * 64 + 255) / 256;       // one wave per node

    // prep + bin_count merged
    prep_bin_kernel<<<NWG_A + 64, 256, 0, stream>>>(
        pw1, sw1, nw1, pw2, sw2, nw2, sb1, nb1, sb2, nb2,
        wb_p1, wb_s1, wb_n1, wb_p2, wb_s2, wb_n2, b_sn1, b_sn2,
        dst, wgcnt, E, NB);
    bin_scan_kernel<<<1, 1024, 0, stream>>>(wgcnt, binoff, NB);
    // bin_scatter + pool1 GEMM merged
    scatter_pool_kernel<<<NWG_A + gemm_grid, 256, 0, stream>>>(
        src, dst, binoff, binned, E, NB,
        in_feat, wb_p1, pb1, mb, M);
    csr_build_kernel<<<NB, 1024, 0, stream>>>(binned, binoff, csr, offsets, counts, M);

    // ---- Layer 1 ----
    gather_max_kernel<<<gather_grid, 256, 0, stream>>>(
        (const u16x8*)mb, csr, offsets, counts, (u16x8*)agg, M);
    sn_pool_kernel<<<gemm_grid, 256, 0, stream>>>(
        in_feat, wb_s1, agg, wb_n1, b_sn1, wb_p2, pb2, h1, mb, M);

    // ---- Layer 2 ----
    gather_max_kernel<<<gather_grid, 256, 0, stream>>>(
        (const u16x8*)mb, csr, offsets, counts, (u16x8*)agg, M);
    mfma_gemm_kernel<3, false, 2, true><<<gemm_grid, 256, 0, stream>>>(
        h1, wb_s2, agg, wb_n2, b_sn2, out, M, 40);
}

// Round 10
// 376.875 us; speedup vs baseline: 1.5092x; 1.0390x over previous
//
#include <hip/hip_runtime.h>

// GraphSAGE (pool aggregator, 2 layers) on MI355X.
// Round 10:
//   - revert r9's nontemporal store on binned: NT bypasses L2 so scattered
//     4B stores became partial-line HBM writes (41 MB for 6.4 MB payload,
//     scatter_pool WRITE=66MB). Plain stores let wg-private sequential
//     streams write-combine in L2.
//   - sn_pool: stage B in K-halves (Bs 34.8->16.9 KB; total LDS ~51 KB) ->
//     3 blocks/CU instead of 2. No extra global traffic, one extra barrier
//     per pass.
// Gathers (fabric-floor, 70% occ), CSR build, final GEMM unchanged.

#define N_FEAT 128
#define NWG_A 256
#define BSHIFT 10            // 1024 nodes per bucket
#define NBMAX 128

typedef __attribute__((ext_vector_type(8))) short bf16x8;            // 8 bf16 = 4 VGPRs
typedef __attribute__((ext_vector_type(8))) unsigned short u16x8;    // 16 B
typedef __attribute__((ext_vector_type(4))) float f32x4;

static __device__ __forceinline__ unsigned short f2bf(float f) {
    unsigned u = __float_as_uint(f);
    unsigned r = (u + 0x7fffu + ((u >> 16) & 1u)) >> 16;   // RNE
    return (unsigned short)r;
}

static __device__ __forceinline__ bf16x8 loadA_f32(const float* __restrict__ A, size_t idx) {
    float4 a = *(const float4*)&A[idx];
    float4 b = *(const float4*)&A[idx + 4];
    bf16x8 r;
    r[0] = (short)f2bf(a.x); r[1] = (short)f2bf(a.y);
    r[2] = (short)f2bf(a.z); r[3] = (short)f2bf(a.w);
    r[4] = (short)f2bf(b.x); r[5] = (short)f2bf(b.y);
    r[6] = (short)f2bf(b.z); r[7] = (short)f2bf(b.w);
    return r;
}

// ---------------- prep (weights->bf16, fused biases) + bin_count merged ----------------
__global__ __launch_bounds__(256) void prep_bin_kernel(
    const float* __restrict__ pw1, const float* __restrict__ sw1,
    const float* __restrict__ nw1, const float* __restrict__ pw2,
    const float* __restrict__ sw2, const float* __restrict__ nw2,
    const float* __restrict__ sb1, const float* __restrict__ nb1,
    const float* __restrict__ sb2, const float* __restrict__ nb2,
    unsigned short* __restrict__ wb_p1, unsigned short* __restrict__ wb_s1,
    unsigned short* __restrict__ wb_n1, unsigned short* __restrict__ wb_p2,
    unsigned short* __restrict__ wb_s2, unsigned short* __restrict__ wb_n2,
    float* __restrict__ b_sn1, float* __restrict__ b_sn2,
    const int* __restrict__ dst, int* __restrict__ wgcnt, int E, int NB)
{
    __shared__ int cnt[NBMAX];
    if (blockIdx.x < NWG_A) {
        const int wg = blockIdx.x, tid = threadIdx.x;
        if (tid < NB) cnt[tid] = 0;
        __syncthreads();
        const int slab = (E + NWG_A - 1) / NWG_A;
        const int e0 = wg * slab;
        const int e1 = min(e0 + slab, E);
        for (int e = e0 + tid; e < e1; e += 256)
            atomicAdd(&cnt[dst[e] >> BSHIFT], 1);
        __syncthreads();
        if (tid < NB) wgcnt[tid * NWG_A + wg] = cnt[tid];
    } else {
        int t = (blockIdx.x - NWG_A) * 256 + threadIdx.x;
        if (t < 16384) {
            wb_p1[t] = f2bf(pw1[t]);
            wb_s1[t] = f2bf(sw1[t]);
            wb_n1[t] = f2bf(nw1[t]);
            wb_p2[t] = f2bf(pw2[t]);
        }
        if (t < 6144) {                   // 48x128, rows 40..47 zero-padded
            int row = t >> 7;
            wb_s2[t] = (row < 40) ? f2bf(sw2[t]) : 0;
            wb_n2[t] = (row < 40) ? f2bf(nw2[t]) : 0;
        }
        if (t < 128) b_sn1[t] = sb1[t] + nb1[t];
        if (t < 64)  b_sn2[t] = (t < 40) ? (sb2[t] + nb2[t]) : 0.f;
    }
}

// ---------------- bin_scan: 1024-thread exclusive scan of NB*NWG_A counts ----------------
__global__ __launch_bounds__(1024) void bin_scan_kernel(const int* __restrict__ wgcnt,
                                                        int* __restrict__ binoff, int NB)
{
    __shared__ int sh[1024];
    const int t = threadIdx.x;
    const int total = NB * NWG_A;
    const int chunk = (total + 1023) / 1024;
    const int b0 = t * chunk;
    const int b1 = min(b0 + chunk, total);
    int s = 0;
    for (int k = b0; k < b1; k++) s += wgcnt[k];
    sh[t] = s;
    __syncthreads();
    for (int off = 1; off < 1024; off <<= 1) {
        int x = (t >= off) ? sh[t - off] : 0;
        __syncthreads();
        sh[t] += x;
        __syncthreads();
    }
    int run = sh[t] - s;
    for (int k = b0; k < b1; k++) {
        int v = wgcnt[k];
        binoff[k] = run;
        run += v;
    }
    if (t == 1023) binoff[total] = sh[1023];   // == E
}

// ---------------- scatter_pool: bin_scatter (blocks 0..255) + pool1 GEMM ----------------
__global__ __launch_bounds__(256, 4) void scatter_pool_kernel(
    const int* __restrict__ src, const int* __restrict__ dst,
    const int* __restrict__ binoff, unsigned* __restrict__ binned, int E, int NB,
    const float* __restrict__ A0f, const unsigned short* __restrict__ B0,
    const float* __restrict__ bias, unsigned short* __restrict__ Cout, int M)
{
    __shared__ int cur[NBMAX];
    __shared__ unsigned short Bs[128 * 136];
    __shared__ float BsF[128];

    if (blockIdx.x < NWG_A) {
        // ---- bin_scatter body (plain stores: L2 write-combines wg-private streams) ----
        const int wg = blockIdx.x, tid = threadIdx.x;
        if (tid < NB) cur[tid] = binoff[tid * NWG_A + wg];
        __syncthreads();
        const int slab = (E + NWG_A - 1) / NWG_A;
        const int e0 = wg * slab;
        const int e1 = min(e0 + slab, E);
        for (int e = e0 + tid; e < e1; e += 256) {
            int d = dst[e];
            int b = d >> BSHIFT;
            unsigned rec = ((unsigned)(d & ((1 << BSHIFT) - 1)) << 17) | (unsigned)src[e];
            int p = atomicAdd(&cur[b], 1);
            binned[p] = rec;
        }
        return;
    }

    // ---- pool1 GEMM body ----
    const int tid = threadIdx.x;
    const int w = tid >> 6, lane = tid & 63;
    const int q = lane >> 4, r16 = lane & 15;
    const int m0 = (blockIdx.x - NWG_A) * 128;

    if (tid < 128) BsF[tid] = bias[tid];

    int rowA[2];
#pragma unroll
    for (int rt = 0; rt < 2; rt++) {
        int r = m0 + w * 32 + rt * 16 + r16;
        rowA[rt] = r < M ? r : (M - 1);
    }

    f32x4 acc[2][8];
#pragma unroll
    for (int i = 0; i < 2; i++)
#pragma unroll
        for (int j = 0; j < 8; j++) acc[i][j] = (f32x4){0.f, 0.f, 0.f, 0.f};

    for (int j = tid; j < 2048; j += 256) {
        int row = j >> 4, cc = j & 15;
        *(uint4*)&Bs[row * 136 + cc * 8] = *(const uint4*)&B0[(size_t)row * 128 + cc * 8];
    }
    __syncthreads();

#pragma unroll
    for (int k0 = 0; k0 < 128; k0 += 32) {
        bf16x8 af[2];
#pragma unroll
        for (int rt = 0; rt < 2; rt++)
            af[rt] = loadA_f32(A0f, (size_t)rowA[rt] * 128 + k0 + q * 8);
#pragma unroll
        for (int ct = 0; ct < 8; ct++) {
            bf16x8 bfr = *(const bf16x8*)&Bs[(ct * 16 + r16) * 136 + k0 + q * 8];
#pragma unroll
            for (int rt = 0; rt < 2; rt++)
                acc[rt][ct] = __builtin_amdgcn_mfma_f32_16x16x32_bf16(
                    af[rt], bfr, acc[rt][ct], 0, 0, 0);
        }
    }

#pragma unroll
    for (int rt = 0; rt < 2; rt++) {
#pragma unroll
        for (int ct = 0; ct < 8; ct++) {
            int col = ct * 16 + r16;
#pragma unroll
            for (int r = 0; r < 4; r++) {
                int grow = m0 + w * 32 + rt * 16 + q * 4 + r;
                if (grow < M) {
                    float v = fmaxf(acc[rt][ct][r] + BsF[col], 0.f);
                    Cout[(size_t)grow * 128 + col] = f2bf(v);
                }
            }
        }
    }
}

// ---------------- csr_build: 1024 threads, thread t owns node t of the bucket ----------------
__global__ __launch_bounds__(1024) void csr_build_kernel(const unsigned* __restrict__ binned,
                                                         const int* __restrict__ binoff,
                                                         int* __restrict__ csr,
                                                         int* __restrict__ offsets,
                                                         int* __restrict__ counts, int M)
{
    __shared__ int cnt[1 << BSHIFT];
    __shared__ int pref[1 << BSHIFT];
    const int b = blockIdx.x, t = threadIdx.x;
    const int rs = binoff[b * NWG_A];
    const int re = binoff[(b + 1) * NWG_A];

    cnt[t] = 0;
    __syncthreads();
    for (int i = rs + t; i < re; i += 1024)
        atomicAdd(&cnt[binned[i] >> 17], 1);
    __syncthreads();

    int v = cnt[t];
    pref[t] = v;
    __syncthreads();
    for (int off = 1; off < 1024; off <<= 1) {
        int x = (t >= off) ? pref[t - off] : 0;
        __syncthreads();
        pref[t] += x;
        __syncthreads();
    }
    int excl = pref[t] - v;

    int node = (b << BSHIFT) + t;
    if (node < M) {
        counts[node] = v;
        offsets[node] = rs + excl;
    }
    cnt[t] = excl;                       // reuse as cursor
    __syncthreads();

    for (int i = rs + t; i < re; i += 1024) {
        unsigned r = binned[i];
        int p = atomicAdd(&cnt[r >> 17], 1);
        csr[rs + p] = (int)(r & 0x1FFFFu);
    }
}

// ---------------- pull gather-max (unchanged; NT store on agg only) ----------------
__global__ __launch_bounds__(256) void gather_max_kernel(
    const u16x8* __restrict__ m16, const int* __restrict__ csr,
    const int* __restrict__ offsets, const int* __restrict__ counts,
    u16x8* __restrict__ agg16, int Nn)
{
    int wid = (blockIdx.x * 256 + threadIdx.x) >> 6;
    int lane = threadIdx.x & 63;
    if (wid >= Nn) return;
    const int g = lane >> 4, c = lane & 15;
    int start = offsets[wid];
    int deg = counts[wid];
    u16x8 acc = (u16x8){0, 0, 0, 0, 0, 0, 0, 0};
    for (int j0 = 0; j0 < deg; j0 += 64) {
        int nb = deg - j0;
        if (nb > 64) nb = 64;
        int sl = csr[start + j0 + (lane < nb ? lane : nb - 1)];
        for (int j = 0; j < nb; j += 4) {
            int jj = j + g;
            if (jj >= nb) jj = nb - 1;
            int s = __shfl(sl, jj);
            u16x8 v = m16[(size_t)s * 16 + c];
            acc = __builtin_elementwise_max(acc, v);
        }
    }
#pragma unroll
    for (int d = 16; d <= 32; d <<= 1) {
        int4 a = *(int4*)&acc;
        int4 t;
        t.x = __shfl_xor(a.x, d);
        t.y = __shfl_xor(a.y, d);
        t.z = __shfl_xor(a.z, d);
        t.w = __shfl_xor(a.w, d);
        acc = __builtin_elementwise_max(acc, *(u16x8*)&t);
    }
    if (g == 0) __builtin_nontemporal_store(acc, &agg16[(size_t)wid * 16 + c]);
}

// ---------------- generic MFMA GEMM (final layer): A direct from global, B-only LDS ----------------
template<int NT, bool RELU, int NPAIRS, bool F32OUT>
__global__ __launch_bounds__(256, 4) void mfma_gemm_kernel(
    const unsigned short* __restrict__ A0, const unsigned short* __restrict__ B0,
    const unsigned short* __restrict__ A1, const unsigned short* __restrict__ B1,
    const float* __restrict__ bias, void* __restrict__ Cout, int M, int Nout)
{
    constexpr int NR = NT * 16;
    __shared__ unsigned short Bs[NR * 136];
    __shared__ float BsF[NR];

    const int tid = threadIdx.x;
    const int w = tid >> 6, lane = tid & 63;
    const int q = lane >> 4, r16 = lane & 15;
    const int m0 = blockIdx.x * 128;

    if (tid < NR) BsF[tid] = (tid < Nout) ? bias[tid] : 0.f;

    int rowA[2];
#pragma unroll
    for (int rt = 0; rt < 2; rt++) {
        int r = m0 + w * 32 + rt * 16 + r16;
        rowA[rt] = r < M ? r : (M - 1);
    }

    f32x4 acc[2][NT];
#pragma unroll
    for (int i = 0; i < 2; i++)
#pragma unroll
        for (int j = 0; j < NT; j++) acc[i][j] = (f32x4){0.f, 0.f, 0.f, 0.f};

    for (int p = 0; p < NPAIRS; p++) {
        const unsigned short* __restrict__ B = p ? B1 : B0;
        const unsigned short* __restrict__ A = p ? A1 : A0;
        if (p) __syncthreads();
        for (int j = tid; j < NR * 16; j += 256) {
            int row = j >> 4, cc = j & 15;
            uint4 v = *(const uint4*)&B[(size_t)row * 128 + cc * 8];
            *(uint4*)&Bs[row * 136 + cc * 8] = v;
        }
        __syncthreads();

#pragma unroll
        for (int k0 = 0; k0 < 128; k0 += 32) {
            bf16x8 af[2];
#pragma unroll
            for (int rt = 0; rt < 2; rt++)
                af[rt] = *(const bf16x8*)&A[(size_t)rowA[rt] * 128 + k0 + q * 8];
#pragma unroll
            for (int ct = 0; ct < NT; ct++) {
                bf16x8 bfr = *(const bf16x8*)&Bs[(ct * 16 + r16) * 136 + k0 + q * 8];
#pragma unroll
                for (int rt = 0; rt < 2; rt++)
                    acc[rt][ct] = __builtin_amdgcn_mfma_f32_16x16x32_bf16(
                        af[rt], bfr, acc[rt][ct], 0, 0, 0);
            }
        }
    }

#pragma unroll
    for (int rt = 0; rt < 2; rt++) {
#pragma unroll
        for (int ct = 0; ct < NT; ct++) {
            int col = ct * 16 + r16;
#pragma unroll
            for (int r = 0; r < 4; r++) {
                int grow = m0 + w * 32 + rt * 16 + q * 4 + r;
                float v = acc[rt][ct][r] + BsF[col];
                if (RELU) v = fmaxf(v, 0.f);
                if (grow < M && col < Nout) {
                    if (F32OUT)
                        ((float*)Cout)[(size_t)grow * Nout + col] = v;
                    else
                        ((unsigned short*)Cout)[(size_t)grow * Nout + col] = f2bf(v);
                }
            }
        }
    }
}

// ---------------- sn_pool: K-halved B staging -> 3 blocks/CU ----------------
// h1 = relu(in@sw1^T + agg@nw1^T + b_sn); m2 = relu(h1@pw2^T + b_p)
// LDS: Bs 128x66 (16.9 KB, half-K) + H 128x132 (33.8 KB) + BsF = ~51 KB.
__global__ __launch_bounds__(256, 3) void sn_pool_kernel(
    const float* __restrict__ A0f, const unsigned short* __restrict__ B0,
    const unsigned short* __restrict__ A1, const unsigned short* __restrict__ B1,
    const float* __restrict__ bias_sn, const unsigned short* __restrict__ Bp,
    const float* __restrict__ bias_p, unsigned short* __restrict__ h1out,
    unsigned short* __restrict__ m2out, int M)
{
    __shared__ unsigned short Bs[128 * 66];    // 128 cols x 64 k, stride 66
    __shared__ unsigned short H[128 * 132];
    __shared__ float BsF[128];

    const int tid = threadIdx.x;
    const int w = tid >> 6, lane = tid & 63;
    const int q = lane >> 4, r16 = lane & 15;
    const int m0 = blockIdx.x * 128;

    if (tid < 128) BsF[tid] = bias_sn[tid];

    int rowA[2];
#pragma unroll
    for (int rt = 0; rt < 2; rt++) {
        int r = m0 + w * 32 + rt * 16 + r16;
        rowA[rt] = r < M ? r : (M - 1);
    }

    f32x4 acc[2][8];
#pragma unroll
    for (int i = 0; i < 2; i++)
#pragma unroll
        for (int j = 0; j < 8; j++) acc[i][j] = (f32x4){0.f, 0.f, 0.f, 0.f};

    // ---- passes 1+2: self (A0 f32) then neigh (A1 bf16), accumulate ----
    for (int p = 0; p < 2; p++) {
        const unsigned short* __restrict__ B = p ? B1 : B0;
        for (int kh = 0; kh < 2; kh++) {
            __syncthreads();               // previous Bs stage consumed
            for (int j = tid; j < 1024; j += 256) {
                int row = j >> 3, cc = j & 7;
                *(uint4*)&Bs[row * 66 + cc * 8] =
                    *(const uint4*)&B[(size_t)row * 128 + kh * 64 + cc * 8];
            }
            __syncthreads();
#pragma unroll
            for (int k0i = 0; k0i < 2; k0i++) {
                const int k0 = kh * 64 + k0i * 32;
                const int koff = k0i * 32;
                bf16x8 af[2];
#pragma unroll
                for (int rt = 0; rt < 2; rt++) {
                    if (p == 0)
                        af[rt] = loadA_f32(A0f, (size_t)rowA[rt] * 128 + k0 + q * 8);
                    else
                        af[rt] = *(const bf16x8*)&A1[(size_t)rowA[rt] * 128 + k0 + q * 8];
                }
#pragma unroll
                for (int ct = 0; ct < 8; ct++) {
                    bf16x8 bfr = *(const bf16x8*)&Bs[(ct * 16 + r16) * 66 + koff + q * 8];
#pragma unroll
                    for (int rt = 0; rt < 2; rt++)
                        acc[rt][ct] = __builtin_amdgcn_mfma_f32_16x16x32_bf16(
                            af[rt], bfr, acc[rt][ct], 0, 0, 0);
                }
            }
        }
    }

    // epilogue 1: h1 = relu(acc + b_sn); write global + H tile
#pragma unroll
    for (int rt = 0; rt < 2; rt++) {
#pragma unroll
        for (int ct = 0; ct < 8; ct++) {
            int col = ct * 16 + r16;
#pragma unroll
            for (int r = 0; r < 4; r++) {
                int lr = w * 32 + rt * 16 + q * 4 + r;
                int grow = m0 + lr;
                float v = fmaxf(acc[rt][ct][r] + BsF[col], 0.f);
                unsigned short hb = f2bf(v);
                H[lr * 132 + col] = hb;
                if (grow < M) h1out[(size_t)grow * 128 + col] = hb;
            }
        }
    }
    __syncthreads();                       // H complete; BsF(bias_sn) reads done
    if (tid < 128) BsF[tid] = bias_p[tid];

#pragma unroll
    for (int i = 0; i < 2; i++)
#pragma unroll
        for (int j = 0; j < 8; j++) acc[i][j] = (f32x4){0.f, 0.f, 0.f, 0.f};

    // ---- pass 3: pool2, A from H ----
    for (int kh = 0; kh < 2; kh++) {
        __syncthreads();                   // Bs stage consumed (also publishes BsF)
        for (int j = tid; j < 1024; j += 256) {
            int row = j >> 3, cc = j & 7;
            *(uint4*)&Bs[row * 66 + cc * 8] =
                *(const uint4*)&Bp[(size_t)row * 128 + kh * 64 + cc * 8];
        }
        __syncthreads();
#pragma unroll
        for (int k0i = 0; k0i < 2; k0i++) {
            const int k0 = kh * 64 + k0i * 32;
            const int koff = k0i * 32;
            bf16x8 af[2];
#pragma unroll
            for (int rt = 0; rt < 2; rt++)
                af[rt] = *(const bf16x8*)&H[(w * 32 + rt * 16 + r16) * 132 + k0 + q * 8];
#pragma unroll
            for (int ct = 0; ct < 8; ct++) {
                bf16x8 bfr = *(const bf16x8*)&Bs[(ct * 16 + r16) * 66 + koff + q * 8];
#pragma unroll
                for (int rt = 0; rt < 2; rt++)
                    acc[rt][ct] = __builtin_amdgcn_mfma_f32_16x16x32_bf16(
                        af[rt], bfr, acc[rt][ct], 0, 0, 0);
            }
        }
    }

#pragma unroll
    for (int rt = 0; rt < 2; rt++) {
#pragma unroll
        for (int ct = 0; ct < 8; ct++) {
            int col = ct * 16 + r16;
#pragma unroll
            for (int r = 0; r < 4; r++) {
                int grow = m0 + w * 32 + rt * 16 + q * 4 + r;
                if (grow < M) {
                    float v = fmaxf(acc[rt][ct][r] + BsF[col], 0.f);
                    m2out[(size_t)grow * 128 + col] = f2bf(v);
                }
            }
        }
    }
}

extern "C" void kernel_launch(void* const* d_in, const int* in_sizes, int n_in,
                              void* d_out, int out_size, void* d_ws, size_t ws_size,
                              hipStream_t stream)
{
    const float* in_feat = (const float*)d_in[0];
    const int*   src     = (const int*)d_in[1];
    const int*   dst     = (const int*)d_in[2];
    const float* pw1 = (const float*)d_in[3];  const float* pb1 = (const float*)d_in[4];
    const float* sw1 = (const float*)d_in[5];  const float* sb1 = (const float*)d_in[6];
    const float* nw1 = (const float*)d_in[7];  const float* nb1 = (const float*)d_in[8];
    const float* pw2 = (const float*)d_in[9];  const float* pb2 = (const float*)d_in[10];
    const float* sw2 = (const float*)d_in[11]; const float* sb2 = (const float*)d_in[12];
    const float* nw2 = (const float*)d_in[13]; const float* nb2 = (const float*)d_in[14];
    float* out = (float*)d_out;

    const int M = in_sizes[0] / N_FEAT;   // 100000 nodes
    const int E = in_sizes[1];            // 1600000 edges
    const int NB = (M + (1 << BSHIFT) - 1) >> BSHIFT;   // 98 buckets

    // ---- workspace layout (256B-aligned regions) ----
    char* base = (char*)d_ws;
    size_t off = 0;
    auto alloc = [&](size_t bytes) { char* p = base + off; off = (off + bytes + 255) & ~(size_t)255; return p; };
    unsigned short* wb_p1 = (unsigned short*)alloc(16384 * 2);
    unsigned short* wb_s1 = (unsigned short*)alloc(16384 * 2);
    unsigned short* wb_n1 = (unsigned short*)alloc(16384 * 2);
    unsigned short* wb_p2 = (unsigned short*)alloc(16384 * 2);
    unsigned short* wb_s2 = (unsigned short*)alloc(6144 * 2);
    unsigned short* wb_n2 = (unsigned short*)alloc(6144 * 2);
    float* b_sn1 = (float*)alloc(128 * 4);
    float* b_sn2 = (float*)alloc(64 * 4);
    unsigned short* mb   = (unsigned short*)alloc((size_t)M * 128 * 2);
    unsigned short* agg  = (unsigned short*)alloc((size_t)M * 128 * 2);
    unsigned short* h1   = (unsigned short*)alloc((size_t)M * 128 * 2);
    int* counts  = (int*)alloc((size_t)M * 4);
    int* offsets = (int*)alloc((size_t)M * 4);
    int* wgcnt   = (int*)alloc((size_t)NB * NWG_A * 4);
    int* binoff  = (int*)alloc(((size_t)NB * NWG_A + 1) * 4);
    unsigned* binned = (unsigned*)alloc((size_t)E * 4);
    int* csr     = (int*)alloc((size_t)E * 4);

    const int gemm_grid = (M + 127) / 128;              // 782
    const int gather_grid = (M * 64 + 255) / 256;       // one wave per node

    // prep + bin_count merged
    prep_bin_kernel<<<NWG_A + 64, 256, 0, stream>>>(
        pw1, sw1, nw1, pw2, sw2, nw2, sb1, nb1, sb2, nb2,
        wb_p1, wb_s1, wb_n1, wb_p2, wb_s2, wb_n2, b_sn1, b_sn2,
        dst, wgcnt, E, NB);
    bin_scan_kernel<<<1, 1024, 0, stream>>>(wgcnt, binoff, NB);
    // bin_scatter + pool1 GEMM merged
    scatter_pool_kernel<<<NWG_A + gemm_grid, 256, 0, stream>>>(
        src, dst, binoff, binned, E, NB,
        in_feat, wb_p1, pb1, mb, M);
    csr_build_kernel<<<NB, 1024, 0, stream>>>(binned, binoff, csr, offsets, counts, M);

    // ---- Layer 1 ----
    gather_max_kernel<<<gather_grid, 256, 0, stream>>>(
        (const u16x8*)mb, csr, offsets, counts, (u16x8*)agg, M);
    sn_pool_kernel<<<gemm_grid, 256, 0, stream>>>(
        in_feat, wb_s1, agg, wb_n1, b_sn1, wb_p2, pb2, h1, mb, M);

    // ---- Layer 2 ----
    gather_max_kernel<<<gather_grid, 256, 0, stream>>>(
        (const u16x8*)mb, csr, offsets, counts, (u16x8*)agg, M);
    mfma_gemm_kernel<3, false, 2, true><<<gemm_grid, 256, 0, stream>>>(
        h1, wb_s2, agg, wb_n2, b_sn2, out, M, 40);
}

// Round 11
// 373.422 us; speedup vs baseline: 1.5231x; 1.0092x over previous
//
#include <hip/hip_runtime.h>

// GraphSAGE (pool aggregator, 2 layers) on MI355X.
// Round 11: fix r10's sn_pool bank conflicts (2.4M conflicts, 79us). Rule:
// LDS row stride in dwords must be ≡4 (mod 32) so each 8-lane b128 phase
// hits a disjoint 4-bank group.
//   Bs half-K: stride 66->72 shorts (36 dw ≡ 4 mod 32), 18.4 KB
//   H:         stride 132->136 shorts (68 dw ≡ 4 mod 32), 34.8 KB
//   total 53.76 KB -> still 3 blocks/CU (161.3 <= 163.8 KB)
// Everything else unchanged from round 10.

#define N_FEAT 128
#define NWG_A 256
#define BSHIFT 10            // 1024 nodes per bucket
#define NBMAX 128

typedef __attribute__((ext_vector_type(8))) short bf16x8;            // 8 bf16 = 4 VGPRs
typedef __attribute__((ext_vector_type(8))) unsigned short u16x8;    // 16 B
typedef __attribute__((ext_vector_type(4))) float f32x4;

static __device__ __forceinline__ unsigned short f2bf(float f) {
    unsigned u = __float_as_uint(f);
    unsigned r = (u + 0x7fffu + ((u >> 16) & 1u)) >> 16;   // RNE
    return (unsigned short)r;
}

static __device__ __forceinline__ bf16x8 loadA_f32(const float* __restrict__ A, size_t idx) {
    float4 a = *(const float4*)&A[idx];
    float4 b = *(const float4*)&A[idx + 4];
    bf16x8 r;
    r[0] = (short)f2bf(a.x); r[1] = (short)f2bf(a.y);
    r[2] = (short)f2bf(a.z); r[3] = (short)f2bf(a.w);
    r[4] = (short)f2bf(b.x); r[5] = (short)f2bf(b.y);
    r[6] = (short)f2bf(b.z); r[7] = (short)f2bf(b.w);
    return r;
}

// ---------------- prep (weights->bf16, fused biases) + bin_count merged ----------------
__global__ __launch_bounds__(256) void prep_bin_kernel(
    const float* __restrict__ pw1, const float* __restrict__ sw1,
    const float* __restrict__ nw1, const float* __restrict__ pw2,
    const float* __restrict__ sw2, const float* __restrict__ nw2,
    const float* __restrict__ sb1, const float* __restrict__ nb1,
    const float* __restrict__ sb2, const float* __restrict__ nb2,
    unsigned short* __restrict__ wb_p1, unsigned short* __restrict__ wb_s1,
    unsigned short* __restrict__ wb_n1, unsigned short* __restrict__ wb_p2,
    unsigned short* __restrict__ wb_s2, unsigned short* __restrict__ wb_n2,
    float* __restrict__ b_sn1, float* __restrict__ b_sn2,
    const int* __restrict__ dst, int* __restrict__ wgcnt, int E, int NB)
{
    __shared__ int cnt[NBMAX];
    if (blockIdx.x < NWG_A) {
        const int wg = blockIdx.x, tid = threadIdx.x;
        if (tid < NB) cnt[tid] = 0;
        __syncthreads();
        const int slab = (E + NWG_A - 1) / NWG_A;
        const int e0 = wg * slab;
        const int e1 = min(e0 + slab, E);
        for (int e = e0 + tid; e < e1; e += 256)
            atomicAdd(&cnt[dst[e] >> BSHIFT], 1);
        __syncthreads();
        if (tid < NB) wgcnt[tid * NWG_A + wg] = cnt[tid];
    } else {
        int t = (blockIdx.x - NWG_A) * 256 + threadIdx.x;
        if (t < 16384) {
            wb_p1[t] = f2bf(pw1[t]);
            wb_s1[t] = f2bf(sw1[t]);
            wb_n1[t] = f2bf(nw1[t]);
            wb_p2[t] = f2bf(pw2[t]);
        }
        if (t < 6144) {                   // 48x128, rows 40..47 zero-padded
            int row = t >> 7;
            wb_s2[t] = (row < 40) ? f2bf(sw2[t]) : 0;
            wb_n2[t] = (row < 40) ? f2bf(nw2[t]) : 0;
        }
        if (t < 128) b_sn1[t] = sb1[t] + nb1[t];
        if (t < 64)  b_sn2[t] = (t < 40) ? (sb2[t] + nb2[t]) : 0.f;
    }
}

// ---------------- bin_scan: 1024-thread exclusive scan of NB*NWG_A counts ----------------
__global__ __launch_bounds__(1024) void bin_scan_kernel(const int* __restrict__ wgcnt,
                                                        int* __restrict__ binoff, int NB)
{
    __shared__ int sh[1024];
    const int t = threadIdx.x;
    const int total = NB * NWG_A;
    const int chunk = (total + 1023) / 1024;
    const int b0 = t * chunk;
    const int b1 = min(b0 + chunk, total);
    int s = 0;
    for (int k = b0; k < b1; k++) s += wgcnt[k];
    sh[t] = s;
    __syncthreads();
    for (int off = 1; off < 1024; off <<= 1) {
        int x = (t >= off) ? sh[t - off] : 0;
        __syncthreads();
        sh[t] += x;
        __syncthreads();
    }
    int run = sh[t] - s;
    for (int k = b0; k < b1; k++) {
        int v = wgcnt[k];
        binoff[k] = run;
        run += v;
    }
    if (t == 1023) binoff[total] = sh[1023];   // == E
}

// ---------------- scatter_pool: bin_scatter (blocks 0..255) + pool1 GEMM ----------------
__global__ __launch_bounds__(256, 4) void scatter_pool_kernel(
    const int* __restrict__ src, const int* __restrict__ dst,
    const int* __restrict__ binoff, unsigned* __restrict__ binned, int E, int NB,
    const float* __restrict__ A0f, const unsigned short* __restrict__ B0,
    const float* __restrict__ bias, unsigned short* __restrict__ Cout, int M)
{
    __shared__ int cur[NBMAX];
    __shared__ unsigned short Bs[128 * 136];
    __shared__ float BsF[128];

    if (blockIdx.x < NWG_A) {
        // ---- bin_scatter body (plain stores: L2 write-combines wg-private streams) ----
        const int wg = blockIdx.x, tid = threadIdx.x;
        if (tid < NB) cur[tid] = binoff[tid * NWG_A + wg];
        __syncthreads();
        const int slab = (E + NWG_A - 1) / NWG_A;
        const int e0 = wg * slab;
        const int e1 = min(e0 + slab, E);
        for (int e = e0 + tid; e < e1; e += 256) {
            int d = dst[e];
            int b = d >> BSHIFT;
            unsigned rec = ((unsigned)(d & ((1 << BSHIFT) - 1)) << 17) | (unsigned)src[e];
            int p = atomicAdd(&cur[b], 1);
            binned[p] = rec;
        }
        return;
    }

    // ---- pool1 GEMM body ----
    const int tid = threadIdx.x;
    const int w = tid >> 6, lane = tid & 63;
    const int q = lane >> 4, r16 = lane & 15;
    const int m0 = (blockIdx.x - NWG_A) * 128;

    if (tid < 128) BsF[tid] = bias[tid];

    int rowA[2];
#pragma unroll
    for (int rt = 0; rt < 2; rt++) {
        int r = m0 + w * 32 + rt * 16 + r16;
        rowA[rt] = r < M ? r : (M - 1);
    }

    f32x4 acc[2][8];
#pragma unroll
    for (int i = 0; i < 2; i++)
#pragma unroll
        for (int j = 0; j < 8; j++) acc[i][j] = (f32x4){0.f, 0.f, 0.f, 0.f};

    for (int j = tid; j < 2048; j += 256) {
        int row = j >> 4, cc = j & 15;
        *(uint4*)&Bs[row * 136 + cc * 8] = *(const uint4*)&B0[(size_t)row * 128 + cc * 8];
    }
    __syncthreads();

#pragma unroll
    for (int k0 = 0; k0 < 128; k0 += 32) {
        bf16x8 af[2];
#pragma unroll
        for (int rt = 0; rt < 2; rt++)
            af[rt] = loadA_f32(A0f, (size_t)rowA[rt] * 128 + k0 + q * 8);
#pragma unroll
        for (int ct = 0; ct < 8; ct++) {
            bf16x8 bfr = *(const bf16x8*)&Bs[(ct * 16 + r16) * 136 + k0 + q * 8];
#pragma unroll
            for (int rt = 0; rt < 2; rt++)
                acc[rt][ct] = __builtin_amdgcn_mfma_f32_16x16x32_bf16(
                    af[rt], bfr, acc[rt][ct], 0, 0, 0);
        }
    }

#pragma unroll
    for (int rt = 0; rt < 2; rt++) {
#pragma unroll
        for (int ct = 0; ct < 8; ct++) {
            int col = ct * 16 + r16;
#pragma unroll
            for (int r = 0; r < 4; r++) {
                int grow = m0 + w * 32 + rt * 16 + q * 4 + r;
                if (grow < M) {
                    float v = fmaxf(acc[rt][ct][r] + BsF[col], 0.f);
                    Cout[(size_t)grow * 128 + col] = f2bf(v);
                }
            }
        }
    }
}

// ---------------- csr_build: 1024 threads, thread t owns node t of the bucket ----------------
__global__ __launch_bounds__(1024) void csr_build_kernel(const unsigned* __restrict__ binned,
                                                         const int* __restrict__ binoff,
                                                         int* __restrict__ csr,
                                                         int* __restrict__ offsets,
                                                         int* __restrict__ counts, int M)
{
    __shared__ int cnt[1 << BSHIFT];
    __shared__ int pref[1 << BSHIFT];
    const int b = blockIdx.x, t = threadIdx.x;
    const int rs = binoff[b * NWG_A];
    const int re = binoff[(b + 1) * NWG_A];

    cnt[t] = 0;
    __syncthreads();
    for (int i = rs + t; i < re; i += 1024)
        atomicAdd(&cnt[binned[i] >> 17], 1);
    __syncthreads();

    int v = cnt[t];
    pref[t] = v;
    __syncthreads();
    for (int off = 1; off < 1024; off <<= 1) {
        int x = (t >= off) ? pref[t - off] : 0;
        __syncthreads();
        pref[t] += x;
        __syncthreads();
    }
    int excl = pref[t] - v;

    int node = (b << BSHIFT) + t;
    if (node < M) {
        counts[node] = v;
        offsets[node] = rs + excl;
    }
    cnt[t] = excl;                       // reuse as cursor
    __syncthreads();

    for (int i = rs + t; i < re; i += 1024) {
        unsigned r = binned[i];
        int p = atomicAdd(&cnt[r >> 17], 1);
        csr[rs + p] = (int)(r & 0x1FFFFu);
    }
}

// ---------------- pull gather-max (unchanged) ----------------
__global__ __launch_bounds__(256) void gather_max_kernel(
    const u16x8* __restrict__ m16, const int* __restrict__ csr,
    const int* __restrict__ offsets, const int* __restrict__ counts,
    u16x8* __restrict__ agg16, int Nn)
{
    int wid = (blockIdx.x * 256 + threadIdx.x) >> 6;
    int lane = threadIdx.x & 63;
    if (wid >= Nn) return;
    const int g = lane >> 4, c = lane & 15;
    int start = offsets[wid];
    int deg = counts[wid];
    u16x8 acc = (u16x8){0, 0, 0, 0, 0, 0, 0, 0};
    for (int j0 = 0; j0 < deg; j0 += 64) {
        int nb = deg - j0;
        if (nb > 64) nb = 64;
        int sl = csr[start + j0 + (lane < nb ? lane : nb - 1)];
        for (int j = 0; j < nb; j += 4) {
            int jj = j + g;
            if (jj >= nb) jj = nb - 1;
            int s = __shfl(sl, jj);
            u16x8 v = m16[(size_t)s * 16 + c];
            acc = __builtin_elementwise_max(acc, v);
        }
    }
#pragma unroll
    for (int d = 16; d <= 32; d <<= 1) {
        int4 a = *(int4*)&acc;
        int4 t;
        t.x = __shfl_xor(a.x, d);
        t.y = __shfl_xor(a.y, d);
        t.z = __shfl_xor(a.z, d);
        t.w = __shfl_xor(a.w, d);
        acc = __builtin_elementwise_max(acc, *(u16x8*)&t);
    }
    if (g == 0) __builtin_nontemporal_store(acc, &agg16[(size_t)wid * 16 + c]);
}

// ---------------- generic MFMA GEMM (final layer): A direct from global, B-only LDS ----------------
template<int NT, bool RELU, int NPAIRS, bool F32OUT>
__global__ __launch_bounds__(256, 4) void mfma_gemm_kernel(
    const unsigned short* __restrict__ A0, const unsigned short* __restrict__ B0,
    const unsigned short* __restrict__ A1, const unsigned short* __restrict__ B1,
    const float* __restrict__ bias, void* __restrict__ Cout, int M, int Nout)
{
    constexpr int NR = NT * 16;
    __shared__ unsigned short Bs[NR * 136];
    __shared__ float BsF[NR];

    const int tid = threadIdx.x;
    const int w = tid >> 6, lane = tid & 63;
    const int q = lane >> 4, r16 = lane & 15;
    const int m0 = blockIdx.x * 128;

    if (tid < NR) BsF[tid] = (tid < Nout) ? bias[tid] : 0.f;

    int rowA[2];
#pragma unroll
    for (int rt = 0; rt < 2; rt++) {
        int r = m0 + w * 32 + rt * 16 + r16;
        rowA[rt] = r < M ? r : (M - 1);
    }

    f32x4 acc[2][NT];
#pragma unroll
    for (int i = 0; i < 2; i++)
#pragma unroll
        for (int j = 0; j < NT; j++) acc[i][j] = (f32x4){0.f, 0.f, 0.f, 0.f};

    for (int p = 0; p < NPAIRS; p++) {
        const unsigned short* __restrict__ B = p ? B1 : B0;
        const unsigned short* __restrict__ A = p ? A1 : A0;
        if (p) __syncthreads();
        for (int j = tid; j < NR * 16; j += 256) {
            int row = j >> 4, cc = j & 15;
            uint4 v = *(const uint4*)&B[(size_t)row * 128 + cc * 8];
            *(uint4*)&Bs[row * 136 + cc * 8] = v;
        }
        __syncthreads();

#pragma unroll
        for (int k0 = 0; k0 < 128; k0 += 32) {
            bf16x8 af[2];
#pragma unroll
            for (int rt = 0; rt < 2; rt++)
                af[rt] = *(const bf16x8*)&A[(size_t)rowA[rt] * 128 + k0 + q * 8];
#pragma unroll
            for (int ct = 0; ct < NT; ct++) {
                bf16x8 bfr = *(const bf16x8*)&Bs[(ct * 16 + r16) * 136 + k0 + q * 8];
#pragma unroll
                for (int rt = 0; rt < 2; rt++)
                    acc[rt][ct] = __builtin_amdgcn_mfma_f32_16x16x32_bf16(
                        af[rt], bfr, acc[rt][ct], 0, 0, 0);
            }
        }
    }

#pragma unroll
    for (int rt = 0; rt < 2; rt++) {
#pragma unroll
        for (int ct = 0; ct < NT; ct++) {
            int col = ct * 16 + r16;
#pragma unroll
            for (int r = 0; r < 4; r++) {
                int grow = m0 + w * 32 + rt * 16 + q * 4 + r;
                float v = acc[rt][ct][r] + BsF[col];
                if (RELU) v = fmaxf(v, 0.f);
                if (grow < M && col < Nout) {
                    if (F32OUT)
                        ((float*)Cout)[(size_t)grow * Nout + col] = v;
                    else
                        ((unsigned short*)Cout)[(size_t)grow * Nout + col] = f2bf(v);
                }
            }
        }
    }
}

// ---------------- sn_pool: K-halved B staging, conflict-free strides, 3 blocks/CU ----------------
// h1 = relu(in@sw1^T + agg@nw1^T + b_sn); m2 = relu(h1@pw2^T + b_p)
// LDS: Bs 128x72 shorts (36 dw ≡ 4 mod 32, 18.4 KB) + H 128x136 (68 dw ≡ 4,
// 34.8 KB) + BsF = 53.76 KB -> 3 blocks/CU, zero bank conflicts.
__global__ __launch_bounds__(256, 3) void sn_pool_kernel(
    const float* __restrict__ A0f, const unsigned short* __restrict__ B0,
    const unsigned short* __restrict__ A1, const unsigned short* __restrict__ B1,
    const float* __restrict__ bias_sn, const unsigned short* __restrict__ Bp,
    const float* __restrict__ bias_p, unsigned short* __restrict__ h1out,
    unsigned short* __restrict__ m2out, int M)
{
    __shared__ unsigned short Bs[128 * 72];    // 128 cols x 64 k, stride 72 shorts
    __shared__ unsigned short H[128 * 136];
    __shared__ float BsF[128];

    const int tid = threadIdx.x;
    const int w = tid >> 6, lane = tid & 63;
    const int q = lane >> 4, r16 = lane & 15;
    const int m0 = blockIdx.x * 128;

    if (tid < 128) BsF[tid] = bias_sn[tid];

    int rowA[2];
#pragma unroll
    for (int rt = 0; rt < 2; rt++) {
        int r = m0 + w * 32 + rt * 16 + r16;
        rowA[rt] = r < M ? r : (M - 1);
    }

    f32x4 acc[2][8];
#pragma unroll
    for (int i = 0; i < 2; i++)
#pragma unroll
        for (int j = 0; j < 8; j++) acc[i][j] = (f32x4){0.f, 0.f, 0.f, 0.f};

    // ---- passes 1+2: self (A0 f32) then neigh (A1 bf16), accumulate ----
    for (int p = 0; p < 2; p++) {
        const unsigned short* __restrict__ B = p ? B1 : B0;
        for (int kh = 0; kh < 2; kh++) {
            __syncthreads();               // previous Bs stage consumed
            for (int j = tid; j < 1024; j += 256) {
                int row = j >> 3, cc = j & 7;
                *(uint4*)&Bs[row * 72 + cc * 8] =
                    *(const uint4*)&B[(size_t)row * 128 + kh * 64 + cc * 8];
            }
            __syncthreads();
#pragma unroll
            for (int k0i = 0; k0i < 2; k0i++) {
                const int k0 = kh * 64 + k0i * 32;
                const int koff = k0i * 32;
                bf16x8 af[2];
#pragma unroll
                for (int rt = 0; rt < 2; rt++) {
                    if (p == 0)
                        af[rt] = loadA_f32(A0f, (size_t)rowA[rt] * 128 + k0 + q * 8);
                    else
                        af[rt] = *(const bf16x8*)&A1[(size_t)rowA[rt] * 128 + k0 + q * 8];
                }
#pragma unroll
                for (int ct = 0; ct < 8; ct++) {
                    bf16x8 bfr = *(const bf16x8*)&Bs[(ct * 16 + r16) * 72 + koff + q * 8];
#pragma unroll
                    for (int rt = 0; rt < 2; rt++)
                        acc[rt][ct] = __builtin_amdgcn_mfma_f32_16x16x32_bf16(
                            af[rt], bfr, acc[rt][ct], 0, 0, 0);
                }
            }
        }
    }

    // epilogue 1: h1 = relu(acc + b_sn); write global + H tile
#pragma unroll
    for (int rt = 0; rt < 2; rt++) {
#pragma unroll
        for (int ct = 0; ct < 8; ct++) {
            int col = ct * 16 + r16;
#pragma unroll
            for (int r = 0; r < 4; r++) {
                int lr = w * 32 + rt * 16 + q * 4 + r;
                int grow = m0 + lr;
                float v = fmaxf(acc[rt][ct][r] + BsF[col], 0.f);
                unsigned short hb = f2bf(v);
                H[lr * 136 + col] = hb;
                if (grow < M) h1out[(size_t)grow * 128 + col] = hb;
            }
        }
    }
    __syncthreads();                       // H complete; BsF(bias_sn) reads done
    if (tid < 128) BsF[tid] = bias_p[tid];

#pragma unroll
    for (int i = 0; i < 2; i++)
#pragma unroll
        for (int j = 0; j < 8; j++) acc[i][j] = (f32x4){0.f, 0.f, 0.f, 0.f};

    // ---- pass 3: pool2, A from H ----
    for (int kh = 0; kh < 2; kh++) {
        __syncthreads();                   // Bs stage consumed (also publishes BsF)
        for (int j = tid; j < 1024; j += 256) {
            int row = j >> 3, cc = j & 7;
            *(uint4*)&Bs[row * 72 + cc * 8] =
                *(const uint4*)&Bp[(size_t)row * 128 + kh * 64 + cc * 8];
        }
        __syncthreads();
#pragma unroll
        for (int k0i = 0; k0i < 2; k0i++) {
            const int k0 = kh * 64 + k0i * 32;
            const int koff = k0i * 32;
            bf16x8 af[2];
#pragma unroll
            for (int rt = 0; rt < 2; rt++)
                af[rt] = *(const bf16x8*)&H[(w * 32 + rt * 16 + r16) * 136 + k0 + q * 8];
#pragma unroll
            for (int ct = 0; ct < 8; ct++) {
                bf16x8 bfr = *(const bf16x8*)&Bs[(ct * 16 + r16) * 72 + koff + q * 8];
#pragma unroll
                for (int rt = 0; rt < 2; rt++)
                    acc[rt][ct] = __builtin_amdgcn_mfma_f32_16x16x32_bf16(
                        af[rt], bfr, acc[rt][ct], 0, 0, 0);
            }
        }
    }

#pragma unroll
    for (int rt = 0; rt < 2; rt++) {
#pragma unroll
        for (int ct = 0; ct < 8; ct++) {
            int col = ct * 16 + r16;
#pragma unroll
            for (int r = 0; r < 4; r++) {
                int grow = m0 + w * 32 + rt * 16 + q * 4 + r;
                if (grow < M) {
                    float v = fmaxf(acc[rt][ct][r] + BsF[col], 0.f);
                    m2out[(size_t)grow * 128 + col] = f2bf(v);
                }
            }
        }
    }
}

extern "C" void kernel_launch(void* const* d_in, const int* in_sizes, int n_in,
                              void* d_out, int out_size, void* d_ws, size_t ws_size,
                              hipStream_t stream)
{
    const float* in_feat = (const float*)d_in[0];
    const int*   src     = (const int*)d_in[1];
    const int*   dst     = (const int*)d_in[2];
    const float* pw1 = (const float*)d_in[3];  const float* pb1 = (const float*)d_in[4];
    const float* sw1 = (const float*)d_in[5];  const float* sb1 = (const float*)d_in[6];
    const float* nw1 = (const float*)d_in[7];  const float* nb1 = (const float*)d_in[8];
    const float* pw2 = (const float*)d_in[9];  const float* pb2 = (const float*)d_in[10];
    const float* sw2 = (const float*)d_in[11]; const float* sb2 = (const float*)d_in[12];
    const float* nw2 = (const float*)d_in[13]; const float* nb2 = (const float*)d_in[14];
    float* out = (float*)d_out;

    const int M = in_sizes[0] / N_FEAT;   // 100000 nodes
    const int E = in_sizes[1];            // 1600000 edges
    const int NB = (M + (1 << BSHIFT) - 1) >> BSHIFT;   // 98 buckets

    // ---- workspace layout (256B-aligned regions) ----
    char* base = (char*)d_ws;
    size_t off = 0;
    auto alloc = [&](size_t bytes) { char* p = base + off; off = (off + bytes + 255) & ~(size_t)255; return p; };
    unsigned short* wb_p1 = (unsigned short*)alloc(16384 * 2);
    unsigned short* wb_s1 = (unsigned short*)alloc(16384 * 2);
    unsigned short* wb_n1 = (unsigned short*)alloc(16384 * 2);
    unsigned short* wb_p2 = (unsigned short*)alloc(16384 * 2);
    unsigned short* wb_s2 = (unsigned short*)alloc(6144 * 2);
    unsigned short* wb_n2 = (unsigned short*)alloc(6144 * 2);
    float* b_sn1 = (float*)alloc(128 * 4);
    float* b_sn2 = (float*)alloc(64 * 4);
    unsigned short* mb   = (unsigned short*)alloc((size_t)M * 128 * 2);
    unsigned short* agg  = (unsigned short*)alloc((size_t)M * 128 * 2);
    unsigned short* h1   = (unsigned short*)alloc((size_t)M * 128 * 2);
    int* counts  = (int*)alloc((size_t)M * 4);
    int* offsets = (int*)alloc((size_t)M * 4);
    int* wgcnt   = (int*)alloc((size_t)NB * NWG_A * 4);
    int* binoff  = (int*)alloc(((size_t)NB * NWG_A + 1) * 4);
    unsigned* binned = (unsigned*)alloc((size_t)E * 4);
    int* csr     = (int*)alloc((size_t)E * 4);

    const int gemm_grid = (M + 127) / 128;              // 782
    const int gather_grid = (M * 64 + 255) / 256;       // one wave per node

    // prep + bin_count merged
    prep_bin_kernel<<<NWG_A + 64, 256, 0, stream>>>(
        pw1, sw1, nw1, pw2, sw2, nw2, sb1, nb1, sb2, nb2,
        wb_p1, wb_s1, wb_n1, wb_p2, wb_s2, wb_n2, b_sn1, b_sn2,
        dst, wgcnt, E, NB);
    bin_scan_kernel<<<1, 1024, 0, stream>>>(wgcnt, binoff, NB);
    // bin_scatter + pool1 GEMM merged
    scatter_pool_kernel<<<NWG_A + gemm_grid, 256, 0, stream>>>(
        src, dst, binoff, binned, E, NB,
        in_feat, wb_p1, pb1, mb, M);
    csr_build_kernel<<<NB, 1024, 0, stream>>>(binned, binoff, csr, offsets, counts, M);

    // ---- Layer 1 ----
    gather_max_kernel<<<gather_grid, 256, 0, stream>>>(
        (const u16x8*)mb, csr, offsets, counts, (u16x8*)agg, M);
    sn_pool_kernel<<<gemm_grid, 256, 0, stream>>>(
        in_feat, wb_s1, agg, wb_n1, b_sn1, wb_p2, pb2, h1, mb, M);

    // ---- Layer 2 ----
    gather_max_kernel<<<gather_grid, 256, 0, stream>>>(
        (const u16x8*)mb, csr, offsets, counts, (u16x8*)agg, M);
    mfma_gemm_kernel<3, false, 2, true><<<gemm_grid, 256, 0, stream>>>(
        h1, wb_s2, agg, wb_n2, b_sn2, out, M, 40);
}